// Round 4
// baseline (195.998 us; speedup 1.0000x reference)
//
#include <hip/hip_runtime.h>
#include <math.h>

#define T_DIM 2048
#define C_DIM 1024
#define B_DIM 8
#define TB    32
#define KROW  72      // bf16 elems per Kc/Qc row (64 + 8 pad)  [fallback kernel]
#define PROW  296     // bf16 elems per P row (288 + 8 pad)

typedef float f32x4 __attribute__((ext_vector_type(4)));
typedef short s16x8 __attribute__((ext_vector_type(8)));

__device__ __forceinline__ unsigned short f2bf(float x) {
    union { float f; unsigned u; } v; v.f = x;
    unsigned r = v.u + 0x7fffu + ((v.u >> 16) & 1u);
    return (unsigned short)(r >> 16);
}
__device__ __forceinline__ unsigned pk2(float a, float b) {
    return (unsigned)f2bf(a) | ((unsigned)f2bf(b) << 16);
}

// =================== pre-pass A: K f32 -> bf16, same row-major layout ===================
// grid (1024, B), 256 thr; block converts 2048 contiguous elems (8/thread)
__global__ __launch_bounds__(256)
void conv_k(const float* __restrict__ K, unsigned short* __restrict__ Kb)
{
    const size_t base = (size_t)blockIdx.y * T_DIM * C_DIM
                      + (size_t)blockIdx.x * 2048 + (size_t)threadIdx.x * 8;
    const float4* src = (const float4*)(K + base);
    float4 x = src[0], y = src[1];
    uint4 o;
    o.x = pk2(x.x, x.y); o.y = pk2(x.z, x.w);
    o.z = pk2(y.x, y.y); o.w = pk2(y.z, y.w);
    *(uint4*)(Kb + base) = o;
}

// =================== pre-pass B: V[b][t][c] f32 -> Vt[b][c][t] bf16 ===================
__global__ __launch_bounds__(256)
void transpose_v(const float* __restrict__ V, unsigned short* __restrict__ Vt)
{
    __shared__ float buf[64 * 67];
    const int t0 = blockIdx.x * 64;
    const int c0 = blockIdx.y * 64;
    const int b  = blockIdx.z;
    const float* Vb = V + (size_t)b * T_DIM * C_DIM;

    for (int i = threadIdx.x; i < 64 * 64; i += 256) {
        const int r = i >> 6, c = i & 63;
        buf[r * 67 + c] = Vb[(size_t)(t0 + r) * C_DIM + c0 + c];
    }
    __syncthreads();
    const int t8 = threadIdx.x & 7;
    const int cl = threadIdx.x >> 3;
#pragma unroll
    for (int half = 0; half < 2; ++half) {
        const int c_loc = cl + half * 32;
        float v[8];
#pragma unroll
        for (int j = 0; j < 8; ++j) v[j] = buf[(t8 * 8 + j) * 67 + c_loc];
        uint4 o;
        o.x = pk2(v[0], v[1]); o.y = pk2(v[2], v[3]);
        o.z = pk2(v[4], v[5]); o.w = pk2(v[6], v[7]);
        *(uint4*)(Vt + (size_t)(b * C_DIM + c0 + c_loc) * T_DIM + t0 + t8 * 8) = o;
    }
}

// =================== banded attention: row-major operands direct from global ===================
// 256 thr = 4 waves (th = t-half of 32-row tile, sh = s-half / c-split).
// aq: Q f32 direct (2 float4/lane) + pack; bk: bf16 K row-major; bv: bf16 Vt row-major.
__global__ __launch_bounds__(256, 2)
void attn_band_rm(const float* __restrict__ Q, const unsigned short* __restrict__ Kb,
                  const unsigned short* __restrict__ Vt,
                  const float* __restrict__ Mask, const int* __restrict__ m_ptr,
                  float* __restrict__ wsrow)
{
    __shared__ short P[32 * PROW];            // 18,944 B
    __shared__ float pmax[64], psum[64], red[64];

    // XCD-bijective swizzle: each XCD owns one batch's contiguous t-range
    const int h = blockIdx.x;
    const int logical = (h & 7) * 64 + (h >> 3);
    const int b  = logical >> 6;
    const int t0 = (logical & 63) * TB;

    const int tid = threadIdx.x;
    const int w = tid >> 6, lane = tid & 63, g = lane >> 4, ln = lane & 15;
    const int th = w >> 1, sh = w & 1;
    const int m  = m_ptr[0];

    const int s_lo = max(0, t0 - m);
    const int s_hi = min(T_DIM - 1, t0 + TB - 1 + m);
    const int sg0  = s_lo >> 5;               // 32-aligned by construction

    const float*          Qb  = Q  + (size_t)b * T_DIM * C_DIM;
    const unsigned short* Kbb = Kb + (size_t)b * T_DIM * C_DIM;
    const unsigned short* Vtb = Vt + (size_t)b * C_DIM * T_DIM;

    // K band rows for this wave's 9 s-tiles (16-row units)
    int srow[9];
#pragma unroll
    for (int i = 0; i < 9; ++i) srow[i] = min(sg0 * 2 + sh * 9 + i, 127) * 16 + ln;

    const float* qrow = Qb + (size_t)(t0 + th * 16 + ln) * C_DIM;

    // ---- phase 1: E = Q.K^T ----
    f32x4 E[9];
    f32x4 zed = {0.f, 0.f, 0.f, 0.f};
#pragma unroll
    for (int i = 0; i < 9; ++i) E[i] = zed;

#pragma unroll 4
    for (int kk = 0; kk < 32; ++kk) {
        const int c0 = kk * 32 + g * 8;
        const float4* qp = (const float4*)(qrow + c0);
        float4 qx = qp[0], qy = qp[1];
        uint4 aqi;
        aqi.x = pk2(qx.x, qx.y); aqi.y = pk2(qx.z, qx.w);
        aqi.z = pk2(qy.x, qy.y); aqi.w = pk2(qy.z, qy.w);
        s16x8 aq = *(s16x8*)&aqi;
#pragma unroll
        for (int i = 0; i < 9; ++i) {
            s16x8 bk = *(const s16x8*)(Kbb + (size_t)srow[i] * C_DIM + c0);
            E[i] = __builtin_amdgcn_mfma_f32_16x16x32_bf16(aq, bk, E[i], 0, 0, 0);
        }
    }

    // ---- phase 2: exact softmax (cross-wave over the two s-halves) ----
    const float scale = 0.03125f;   // 1/sqrt(1024)
    const int rowb = th * 16 + g * 4;
    float lm[4];
#pragma unroll
    for (int r = 0; r < 4; ++r) lm[r] = -INFINITY;
    const int s_base = s_lo + sh * 144 + ln;
#pragma unroll
    for (int i = 0; i < 9; ++i) {
        const int s = s_base + i * 16;
#pragma unroll
        for (int r = 0; r < 4; ++r) {
            const int t = t0 + rowb + r;
            int d = t - s; d = d < 0 ? -d : d;
            const bool valid = (s <= s_hi) && (d <= m);
            float e = valid ? E[i][r] : -INFINITY;
            E[i][r] = e;
            lm[r] = fmaxf(lm[r], e);
        }
    }
#pragma unroll
    for (int r = 0; r < 4; ++r)
#pragma unroll
        for (int dd = 1; dd < 16; dd <<= 1) lm[r] = fmaxf(lm[r], __shfl_xor(lm[r], dd));
    if (ln == 0) {
#pragma unroll
        for (int r = 0; r < 4; ++r) pmax[sh * 32 + rowb + r] = lm[r];
    }
    __syncthreads();
    float Mr[4], sum[4];
#pragma unroll
    for (int r = 0; r < 4; ++r) {
        Mr[r] = fmaxf(pmax[rowb + r], pmax[32 + rowb + r]) * scale;
        sum[r] = 0.f;
    }
#pragma unroll
    for (int i = 0; i < 9; ++i)
#pragma unroll
        for (int r = 0; r < 4; ++r) {
            float e = __expf(E[i][r] * scale - Mr[r]);   // -inf -> 0 exactly
            E[i][r] = e;
            sum[r] += e;
        }
#pragma unroll
    for (int r = 0; r < 4; ++r)
#pragma unroll
        for (int dd = 1; dd < 16; dd <<= 1) sum[r] += __shfl_xor(sum[r], dd);
    if (ln == 0) {
#pragma unroll
        for (int r = 0; r < 4; ++r) psum[sh * 32 + rowb + r] = sum[r];
    }
    __syncthreads();
    float inv[4];
#pragma unroll
    for (int r = 0; r < 4; ++r) inv[r] = 1.0f / (psum[rowb + r] + psum[32 + rowb + r]);
#pragma unroll
    for (int i = 0; i < 9; ++i) {
        const int col = sh * 144 + i * 16 + ln;
#pragma unroll
        for (int r = 0; r < 4; ++r)
            P[(rowb + r) * PROW + col] = (short)f2bf(E[i][r] * inv[r]);
    }
    __syncthreads();

    // ---- phase 3: O = P @ V via Vt row-major; fold masked row-max ----
    s16x8 pa[9];
#pragma unroll
    for (int kg = 0; kg < 9; ++kg)
        pa[kg] = *(const s16x8*)(P + (th * 16 + ln) * PROW + kg * 32 + g * 8);

    int scol[9];
#pragma unroll
    for (int kg = 0; kg < 9; ++kg) scol[kg] = min(sg0 + kg, 63) * 32 + g * 8;

    float maskv[4], rmax[4];
#pragma unroll
    for (int r = 0; r < 4; ++r) {
        maskv[r] = Mask[(size_t)b * T_DIM + t0 + rowb + r];
        rmax[r]  = -INFINITY;
    }

    for (int q = 0; q < 16; ++q) {
        const int ct0 = q * 4 + sh * 2;
        const unsigned short* v0r = Vtb + (size_t)(ct0 * 16 + ln) * T_DIM;
        const unsigned short* v1r = Vtb + (size_t)((ct0 + 1) * 16 + ln) * T_DIM;
        f32x4 O0 = zed, O1 = zed;
#pragma unroll
        for (int kg = 0; kg < 9; ++kg) {
            s16x8 bv0 = *(const s16x8*)(v0r + scol[kg]);
            s16x8 bv1 = *(const s16x8*)(v1r + scol[kg]);
            O0 = __builtin_amdgcn_mfma_f32_16x16x32_bf16(pa[kg], bv0, O0, 0, 0, 0);
            O1 = __builtin_amdgcn_mfma_f32_16x16x32_bf16(pa[kg], bv1, O1, 0, 0, 0);
        }
#pragma unroll
        for (int r = 0; r < 4; ++r) {
            rmax[r] = fmaxf(rmax[r], O0[r] * maskv[r]);
            rmax[r] = fmaxf(rmax[r], O1[r] * maskv[r]);
        }
    }
#pragma unroll
    for (int r = 0; r < 4; ++r)
#pragma unroll
        for (int dd = 1; dd < 16; dd <<= 1) rmax[r] = fmaxf(rmax[r], __shfl_xor(rmax[r], dd));
    if (ln == 0) {
#pragma unroll
        for (int r = 0; r < 4; ++r) red[sh * 32 + rowb + r] = rmax[r];
    }
    __syncthreads();
    if (tid < 32)
        wsrow[(size_t)b * T_DIM + t0 + tid] = fmaxf(red[tid], red[32 + tid]);
}

// =================== fallback (round-1, verified): K/V staged per block ===================
__global__ __launch_bounds__(256, 2)
void attn_band_mfma(const float* __restrict__ Q, const float* __restrict__ K,
                    const unsigned short* __restrict__ Vt,
                    const float* __restrict__ Mask, const int* __restrict__ m_ptr,
                    float* __restrict__ wsrow)
{
    __shared__ __align__(16) char smem_raw[57600];
    short* SM = (short*)smem_raw;
    short* Kc = SM;
    short* Qc = SM + 288 * KROW;
    short* P  = SM;
    short* Vl = SM + 32 * PROW;
    float* pmax = (float*)(smem_raw + 56832);
    float* psum = pmax + 64;
    float* red  = psum + 64;

    const int h = blockIdx.x;
    const int logical = (h & 7) * 64 + (h >> 3);
    const int b  = logical >> 6;
    const int t0 = (logical & 63) * TB;

    const int tid = threadIdx.x;
    const int w = tid >> 6, lane = tid & 63, g = lane >> 4, ln = lane & 15;
    const int th = w >> 1, sh = w & 1;
    const int m  = m_ptr[0];

    const int s_lo = max(0, t0 - m);
    const int s_hi = min(T_DIM - 1, t0 + TB - 1 + m);

    const float* Qb = Q + (size_t)b * T_DIM * C_DIM;
    const float* Kb = K + (size_t)b * T_DIM * C_DIM;
    const unsigned short* Vtb = Vt + (size_t)b * C_DIM * T_DIM;

    f32x4 E[9];
    f32x4 zed = {0.f, 0.f, 0.f, 0.f};
#pragma unroll
    for (int i = 0; i < 9; ++i) E[i] = zed;

    for (int cc = 0; cc < C_DIM / 64; ++cc) {
        const int c0 = cc * 64;
        __syncthreads();
        for (int u = tid; u < 288 * 8; u += 256) {
            const int su = u >> 3, un = u & 7;
            const int s = min(s_lo + su, T_DIM - 1);
            const float4* src = (const float4*)(Kb + (size_t)s * C_DIM + c0 + un * 8);
            float4 x = src[0], y = src[1];
            uint4 o; o.x = pk2(x.x, x.y); o.y = pk2(x.z, x.w);
            o.z = pk2(y.x, y.y); o.w = pk2(y.z, y.w);
            *(uint4*)(Kc + su * KROW + un * 8) = o;
        }
        {
            const int su = tid >> 3, un = tid & 7;
            const float4* src = (const float4*)(Qb + (size_t)(t0 + su) * C_DIM + c0 + un * 8);
            float4 x = src[0], y = src[1];
            uint4 o; o.x = pk2(x.x, x.y); o.y = pk2(x.z, x.w);
            o.z = pk2(y.x, y.y); o.w = pk2(y.z, y.w);
            *(uint4*)(Qc + su * KROW + un * 8) = o;
        }
        __syncthreads();
        s16x8 aq[2];
#pragma unroll
        for (int kk = 0; kk < 2; ++kk)
            aq[kk] = *(const s16x8*)(Qc + (th * 16 + ln) * KROW + kk * 32 + g * 8);
#pragma unroll
        for (int i = 0; i < 9; ++i) {
            const int srow2 = (sh * 9 + i) * 16 + ln;
#pragma unroll
            for (int kk = 0; kk < 2; ++kk) {
                s16x8 bk = *(const s16x8*)(Kc + srow2 * KROW + kk * 32 + g * 8);
                E[i] = __builtin_amdgcn_mfma_f32_16x16x32_bf16(aq[kk], bk, E[i], 0, 0, 0);
            }
        }
    }

    const float scale = 0.03125f;
    const int rowb = th * 16 + g * 4;
    float lm[4];
#pragma unroll
    for (int r = 0; r < 4; ++r) lm[r] = -INFINITY;
    const int s_base = s_lo + sh * 144 + ln;
#pragma unroll
    for (int i = 0; i < 9; ++i) {
        const int s = s_base + i * 16;
#pragma unroll
        for (int r = 0; r < 4; ++r) {
            const int t = t0 + rowb + r;
            int d = t - s; d = d < 0 ? -d : d;
            const bool valid = (s <= s_hi) && (d <= m);
            float e = valid ? E[i][r] : -INFINITY;
            E[i][r] = e;
            lm[r] = fmaxf(lm[r], e);
        }
    }
#pragma unroll
    for (int r = 0; r < 4; ++r)
#pragma unroll
        for (int dd = 1; dd < 16; dd <<= 1) lm[r] = fmaxf(lm[r], __shfl_xor(lm[r], dd));
    if (ln == 0) {
#pragma unroll
        for (int r = 0; r < 4; ++r) pmax[sh * 32 + rowb + r] = lm[r];
    }
    __syncthreads();
    float Mr[4], sum[4];
#pragma unroll
    for (int r = 0; r < 4; ++r) {
        Mr[r] = fmaxf(pmax[rowb + r], pmax[32 + rowb + r]) * scale;
        sum[r] = 0.f;
    }
#pragma unroll
    for (int i = 0; i < 9; ++i)
#pragma unroll
        for (int r = 0; r < 4; ++r) {
            float e = __expf(E[i][r] * scale - Mr[r]);
            E[i][r] = e;
            sum[r] += e;
        }
#pragma unroll
    for (int r = 0; r < 4; ++r)
#pragma unroll
        for (int dd = 1; dd < 16; dd <<= 1) sum[r] += __shfl_xor(sum[r], dd);
    if (ln == 0) {
#pragma unroll
        for (int r = 0; r < 4; ++r) psum[sh * 32 + rowb + r] = sum[r];
    }
    __syncthreads();
    float inv[4];
#pragma unroll
    for (int r = 0; r < 4; ++r) inv[r] = 1.0f / (psum[rowb + r] + psum[32 + rowb + r]);
#pragma unroll
    for (int i = 0; i < 9; ++i) {
        const int col = sh * 144 + i * 16 + ln;
#pragma unroll
        for (int r = 0; r < 4; ++r)
            P[(rowb + r) * PROW + col] = (short)f2bf(E[i][r] * inv[r]);
    }
    __syncthreads();

    s16x8 pa[9];
#pragma unroll
    for (int kg = 0; kg < 9; ++kg)
        pa[kg] = *(const s16x8*)(P + (th * 16 + ln) * PROW + kg * 32 + g * 8);

    float maskv[4], rmax[4];
#pragma unroll
    for (int r = 0; r < 4; ++r) {
        maskv[r] = Mask[(size_t)b * T_DIM + t0 + rowb + r];
        rmax[r]  = -INFINITY;
    }

    for (int cc = 0; cc < C_DIM / 64; ++cc) {
        __syncthreads();
        for (int i2 = tid; i2 < 64 * 36; i2 += 256) {
            const int cr = i2 / 36, un = i2 - cr * 36;
            const int sb = min(s_lo + un * 8, T_DIM - 8);
            uint4 x = *(const uint4*)(Vtb + (size_t)(cc * 64 + cr) * T_DIM + sb);
            *(uint4*)(Vl + cr * PROW + un * 8) = x;
        }
        __syncthreads();
#pragma unroll
        for (int nbi = 0; nbi < 2; ++nbi) {
            const int crow = sh * 32 + nbi * 16 + ln;
            f32x4 O = zed;
#pragma unroll
            for (int kg = 0; kg < 9; ++kg) {
                s16x8 bv = *(const s16x8*)(Vl + crow * PROW + kg * 32 + g * 8);
                O = __builtin_amdgcn_mfma_f32_16x16x32_bf16(pa[kg], bv, O, 0, 0, 0);
            }
#pragma unroll
            for (int r = 0; r < 4; ++r)
                rmax[r] = fmaxf(rmax[r], O[r] * maskv[r]);
        }
    }
#pragma unroll
    for (int r = 0; r < 4; ++r)
#pragma unroll
        for (int dd = 1; dd < 16; dd <<= 1) rmax[r] = fmaxf(rmax[r], __shfl_xor(rmax[r], dd));
    if (ln == 0) {
#pragma unroll
        for (int r = 0; r < 4; ++r) red[sh * 32 + rowb + r] = rmax[r];
    }
    __syncthreads();
    if (tid < 32)
        wsrow[(size_t)b * T_DIM + t0 + tid] = fmaxf(red[tid], red[32 + tid]);
}

// out[b] = sum_t ws[b][t]
__global__ void reduce_b(const float* __restrict__ ws, float* __restrict__ out)
{
    const int b = blockIdx.x;
    float s = 0.f;
    for (int t = threadIdx.x; t < T_DIM; t += 256) s += ws[(size_t)b * T_DIM + t];
#pragma unroll
    for (int dd = 32; dd > 0; dd >>= 1) s += __shfl_xor(s, dd);
    __shared__ float acc[4];
    if ((threadIdx.x & 63) == 0) acc[threadIdx.x >> 6] = s;
    __syncthreads();
    if (threadIdx.x == 0) out[b] = acc[0] + acc[1] + acc[2] + acc[3];
}

extern "C" void kernel_launch(void* const* d_in, const int* in_sizes, int n_in,
                              void* d_out, int out_size, void* d_ws, size_t ws_size,
                              hipStream_t stream)
{
    const float* Q    = (const float*)d_in[0];
    const float* K    = (const float*)d_in[1];
    const float* V    = (const float*)d_in[2];
    const float* Mask = (const float*)d_in[3];
    const int*   m    = (const int*)d_in[4];
    float* out = (float*)d_out;

    const size_t bf16_bytes = (size_t)B_DIM * T_DIM * C_DIM * 2;   // 33,554,432
    const size_t need_main  = 2 * bf16_bytes + (size_t)B_DIM * T_DIM * 4;
    const size_t need_fb    = bf16_bytes + (size_t)B_DIM * T_DIM * 4;

    if (ws_size >= need_main) {
        unsigned short* Vt = (unsigned short*)d_ws;
        unsigned short* Kb = (unsigned short*)((char*)d_ws + bf16_bytes);
        float* wsrow = (float*)((char*)d_ws + 2 * bf16_bytes);
        conv_k<<<dim3(1024, B_DIM), 256, 0, stream>>>(K, Kb);
        transpose_v<<<dim3(T_DIM / 64, C_DIM / 64, B_DIM), 256, 0, stream>>>(V, Vt);
        attn_band_rm<<<dim3((T_DIM / TB) * B_DIM), 256, 0, stream>>>(Q, Kb, Vt, Mask, m, wsrow);
        reduce_b<<<B_DIM, 256, 0, stream>>>(wsrow, out);
    } else {
        unsigned short* Vt = (unsigned short*)d_ws;
        float* wsrow = (float*)((char*)d_ws + bf16_bytes);
        transpose_v<<<dim3(T_DIM / 64, C_DIM / 64, B_DIM), 256, 0, stream>>>(V, Vt);
        attn_band_mfma<<<dim3((T_DIM / TB) * B_DIM), 256, 0, stream>>>(Q, K, Vt, Mask, m, wsrow);
        reduce_b<<<B_DIM, 256, 0, stream>>>(wsrow, out);
    }
}

// Round 5
// 143.948 us; speedup vs baseline: 1.3616x; 1.3616x over previous
//
#include <hip/hip_runtime.h>
#include <math.h>

#define T_DIM 2048
#define C_DIM 1024
#define B_DIM 8
#define TB    32
#define KROW  72      // bf16 elems per Kc/Qc row (64 + 8 pad)  [fallback kernel]
#define PROW  296     // bf16 elems per P row (288 + 8 pad)

typedef float f32x4 __attribute__((ext_vector_type(4)));
typedef short s16x8 __attribute__((ext_vector_type(8)));

__device__ __forceinline__ unsigned short f2bf(float x) {
    union { float f; unsigned u; } v; v.f = x;
    unsigned r = v.u + 0x7fffu + ((v.u >> 16) & 1u);
    return (unsigned short)(r >> 16);
}
__device__ __forceinline__ unsigned pk2(float a, float b) {
    return (unsigned)f2bf(a) | ((unsigned)f2bf(b) << 16);
}

// ============ pre-pass A: K f32 -> fragment-major bf16 Kt[b][tile][kk][lane][8] ============
// elem = K[b][tile*16+(l&15)][kk*32+(l>>4)*8+j].  No LDS, no barriers.
// Per wave-instr: reads 16 rows x 128B (full lines, each byte once); writes 1KB contiguous.
__global__ __launch_bounds__(256)
void tile_k(const float* __restrict__ K, unsigned short* __restrict__ Kt)
{
    const int tile = blockIdx.x;      // 0..127
    const int b    = blockIdx.y;
    const int tid  = threadIdx.x;
    const int w = tid >> 6, l = tid & 63, g = l >> 4, ln = l & 15;
    const float* src_row = K + (size_t)(b * T_DIM + tile * 16 + ln) * C_DIM;
#pragma unroll
    for (int kki = 0; kki < 8; ++kki) {
        const int kk = kki * 4 + w;
        const float4* p = (const float4*)(src_row + kk * 32 + g * 8);
        float4 x = p[0], y = p[1];
        uint4 o;
        o.x = pk2(x.x, x.y); o.y = pk2(x.z, x.w);
        o.z = pk2(y.x, y.y); o.w = pk2(y.z, y.w);
        *(uint4*)(Kt + (size_t)(((b * 128 + tile) * 32 + kk) * 64 + l) * 8) = o;
    }
}

// ============ pre-pass B: V f32 -> bf16, fragment-major Vtt OR row-major Vt ============
// frag_mode=1: Vtt[b][ct][sg][lane][8], elem = V[b][sg*32+(l>>4)*8+j][ct*16+(l&15)]
// frag_mode=0: Vt[b][c][t] row-major (fallback path layout)
__global__ __launch_bounds__(256)
void transpose_vx(const float* __restrict__ V, unsigned short* __restrict__ out,
                  int frag_mode)
{
    __shared__ float buf[64 * 67];
    const int t0 = blockIdx.x * 64;
    const int c0 = blockIdx.y * 64;
    const int b  = blockIdx.z;
    const float* Vb = V + (size_t)b * T_DIM * C_DIM;

    for (int i = threadIdx.x; i < 64 * 64; i += 256) {
        const int r = i >> 6, c = i & 63;
        buf[r * 67 + c] = Vb[(size_t)(t0 + r) * C_DIM + c0 + c];
    }
    __syncthreads();
    const int t8 = threadIdx.x & 7;   // 8-t segment
    const int cl = threadIdx.x >> 3;  // 0..31
#pragma unroll
    for (int half = 0; half < 2; ++half) {
        const int c_loc = cl + half * 32;
        float v[8];
#pragma unroll
        for (int j = 0; j < 8; ++j) v[j] = buf[(t8 * 8 + j) * 67 + c_loc];
        uint4 o;
        o.x = pk2(v[0], v[1]); o.y = pk2(v[2], v[3]);
        o.z = pk2(v[4], v[5]); o.w = pk2(v[6], v[7]);
        if (frag_mode) {
            const int ct = (c0 + c_loc) >> 4, lnv = c_loc & 15;
            const int g = t8 & 3, sg = (t0 >> 5) + (t8 >> 2);
            *(uint4*)(out + (size_t)(((b * 64 + ct) * 64 + sg) * 64 + g * 16 + lnv) * 8) = o;
        } else {
            *(uint4*)(out + (size_t)(b * C_DIM + c0 + c_loc) * T_DIM + t0 + t8 * 8) = o;
        }
    }
}

// ============ banded attention: K/V fragment-major (coalesced 1KB loads), Q f32 direct ============
// 256 thr = 4 waves (th = t-half of 32-row tile, sh = s-half / c-split).
__global__ __launch_bounds__(256, 2)
void attn_band_tiled(const float* __restrict__ Q,
                     const unsigned short* __restrict__ Kt,
                     const unsigned short* __restrict__ Vtt,
                     const float* __restrict__ Mask, const int* __restrict__ m_ptr,
                     float* __restrict__ wsrow)
{
    __shared__ short P[32 * PROW];            // 18,944 B
    __shared__ float pmax[64], psum[64], red[64];

    // XCD-bijective swizzle: each XCD owns one batch's contiguous t-range
    const int h = blockIdx.x;
    const int logical = (h & 7) * 64 + (h >> 3);
    const int b  = logical >> 6;
    const int t0 = (logical & 63) * TB;

    const int tid = threadIdx.x;
    const int w = tid >> 6, lane = tid & 63, g = lane >> 4, ln = lane & 15;
    const int th = w >> 1, sh = w & 1;
    const int m  = m_ptr[0];

    const int s_lo = max(0, t0 - m);
    const int s_hi = min(T_DIM - 1, t0 + TB - 1 + m);
    const int sg0  = s_lo >> 5;               // 32-aligned by construction

    const float*          Qb  = Q   + (size_t)b * T_DIM * C_DIM;
    const unsigned short* Ktb = Kt  + (size_t)b * 128 * 32 * 512;
    const unsigned short* Vtb = Vtt + (size_t)b * 64 * 64 * 512;

    const float* qrow = Qb + (size_t)(t0 + th * 16 + ln) * C_DIM;

    int stg[9];
#pragma unroll
    for (int i = 0; i < 9; ++i) stg[i] = min(sg0 * 2 + sh * 9 + i, 127);

    // ---- phase 1: E = Q.K^T; K fragments coalesced from Kt, Q direct f32 ----
    f32x4 E[9];
    f32x4 zed = {0.f, 0.f, 0.f, 0.f};
#pragma unroll
    for (int i = 0; i < 9; ++i) E[i] = zed;

#pragma unroll 4
    for (int kk = 0; kk < 32; ++kk) {
        const float4* qp = (const float4*)(qrow + kk * 32 + g * 8);
        float4 qx = qp[0], qy = qp[1];
        uint4 aqi;
        aqi.x = pk2(qx.x, qx.y); aqi.y = pk2(qx.z, qx.w);
        aqi.z = pk2(qy.x, qy.y); aqi.w = pk2(qy.z, qy.w);
        s16x8 aq = *(s16x8*)&aqi;
#pragma unroll
        for (int i = 0; i < 9; ++i) {
            s16x8 bk = *(const s16x8*)(Ktb + (size_t)((stg[i] * 32 + kk) * 64 + lane) * 8);
            E[i] = __builtin_amdgcn_mfma_f32_16x16x32_bf16(aq, bk, E[i], 0, 0, 0);
        }
    }

    // ---- phase 2: exact softmax (cross-wave over the two s-halves) ----
    const float scale = 0.03125f;   // 1/sqrt(1024)
    const int rowb = th * 16 + g * 4;
    float lm[4];
#pragma unroll
    for (int r = 0; r < 4; ++r) lm[r] = -INFINITY;
    const int s_base = s_lo + sh * 144 + ln;
#pragma unroll
    for (int i = 0; i < 9; ++i) {
        const int s = s_base + i * 16;
#pragma unroll
        for (int r = 0; r < 4; ++r) {
            const int t = t0 + rowb + r;
            int d = t - s; d = d < 0 ? -d : d;
            const bool valid = (s <= s_hi) && (d <= m);
            float e = valid ? E[i][r] : -INFINITY;
            E[i][r] = e;
            lm[r] = fmaxf(lm[r], e);
        }
    }
#pragma unroll
    for (int r = 0; r < 4; ++r)
#pragma unroll
        for (int dd = 1; dd < 16; dd <<= 1) lm[r] = fmaxf(lm[r], __shfl_xor(lm[r], dd));
    if (ln == 0) {
#pragma unroll
        for (int r = 0; r < 4; ++r) pmax[sh * 32 + rowb + r] = lm[r];
    }
    __syncthreads();
    float Mr[4], sum[4];
#pragma unroll
    for (int r = 0; r < 4; ++r) {
        Mr[r] = fmaxf(pmax[rowb + r], pmax[32 + rowb + r]) * scale;
        sum[r] = 0.f;
    }
#pragma unroll
    for (int i = 0; i < 9; ++i)
#pragma unroll
        for (int r = 0; r < 4; ++r) {
            float e = __expf(E[i][r] * scale - Mr[r]);   // -inf -> 0 exactly
            E[i][r] = e;
            sum[r] += e;
        }
#pragma unroll
    for (int r = 0; r < 4; ++r)
#pragma unroll
        for (int dd = 1; dd < 16; dd <<= 1) sum[r] += __shfl_xor(sum[r], dd);
    if (ln == 0) {
#pragma unroll
        for (int r = 0; r < 4; ++r) psum[sh * 32 + rowb + r] = sum[r];
    }
    __syncthreads();
    float inv[4];
#pragma unroll
    for (int r = 0; r < 4; ++r) inv[r] = 1.0f / (psum[rowb + r] + psum[32 + rowb + r]);
#pragma unroll
    for (int i = 0; i < 9; ++i) {
        const int col = sh * 144 + i * 16 + ln;
#pragma unroll
        for (int r = 0; r < 4; ++r)
            P[(rowb + r) * PROW + col] = (short)f2bf(E[i][r] * inv[r]);
    }
    __syncthreads();

    // ---- phase 3: O = P @ V, V fragments coalesced from Vtt; fold masked row-max ----
    s16x8 pa[9];
#pragma unroll
    for (int kg = 0; kg < 9; ++kg)
        pa[kg] = *(const s16x8*)(P + (th * 16 + ln) * PROW + kg * 32 + g * 8);

    int sgc[9];
#pragma unroll
    for (int kg = 0; kg < 9; ++kg) sgc[kg] = min(sg0 + kg, 63);

    float maskv[4], rmax[4];
#pragma unroll
    for (int r = 0; r < 4; ++r) {
        maskv[r] = Mask[(size_t)b * T_DIM + t0 + rowb + r];
        rmax[r]  = -INFINITY;
    }

    for (int q = 0; q < 16; ++q) {
        const int ct0 = q * 4 + sh * 2;
        f32x4 O0 = zed, O1 = zed;
#pragma unroll
        for (int kg = 0; kg < 9; ++kg) {
            s16x8 bv0 = *(const s16x8*)(Vtb + (size_t)(((ct0    ) * 64 + sgc[kg]) * 64 + lane) * 8);
            s16x8 bv1 = *(const s16x8*)(Vtb + (size_t)(((ct0 + 1) * 64 + sgc[kg]) * 64 + lane) * 8);
            O0 = __builtin_amdgcn_mfma_f32_16x16x32_bf16(pa[kg], bv0, O0, 0, 0, 0);
            O1 = __builtin_amdgcn_mfma_f32_16x16x32_bf16(pa[kg], bv1, O1, 0, 0, 0);
        }
#pragma unroll
        for (int r = 0; r < 4; ++r) {
            rmax[r] = fmaxf(rmax[r], O0[r] * maskv[r]);
            rmax[r] = fmaxf(rmax[r], O1[r] * maskv[r]);
        }
    }
#pragma unroll
    for (int r = 0; r < 4; ++r)
#pragma unroll
        for (int dd = 1; dd < 16; dd <<= 1) rmax[r] = fmaxf(rmax[r], __shfl_xor(rmax[r], dd));
    if (ln == 0) {
#pragma unroll
        for (int r = 0; r < 4; ++r) red[sh * 32 + rowb + r] = rmax[r];
    }
    __syncthreads();
    if (tid < 32)
        wsrow[(size_t)b * T_DIM + t0 + tid] = fmaxf(red[tid], red[32 + tid]);
}

// ============ fallback (round-1, verified): K/V staged per block, Vt row-major ============
__global__ __launch_bounds__(256, 2)
void attn_band_mfma(const float* __restrict__ Q, const float* __restrict__ K,
                    const unsigned short* __restrict__ Vt,
                    const float* __restrict__ Mask, const int* __restrict__ m_ptr,
                    float* __restrict__ wsrow)
{
    __shared__ __align__(16) char smem_raw[57600];
    short* SM = (short*)smem_raw;
    short* Kc = SM;
    short* Qc = SM + 288 * KROW;
    short* P  = SM;
    short* Vl = SM + 32 * PROW;
    float* pmax = (float*)(smem_raw + 56832);
    float* psum = pmax + 64;
    float* red  = psum + 64;

    const int h = blockIdx.x;
    const int logical = (h & 7) * 64 + (h >> 3);
    const int b  = logical >> 6;
    const int t0 = (logical & 63) * TB;

    const int tid = threadIdx.x;
    const int w = tid >> 6, lane = tid & 63, g = lane >> 4, ln = lane & 15;
    const int th = w >> 1, sh = w & 1;
    const int m  = m_ptr[0];

    const int s_lo = max(0, t0 - m);
    const int s_hi = min(T_DIM - 1, t0 + TB - 1 + m);

    const float* Qb = Q + (size_t)b * T_DIM * C_DIM;
    const float* Kb = K + (size_t)b * T_DIM * C_DIM;
    const unsigned short* Vtb = Vt + (size_t)b * C_DIM * T_DIM;

    f32x4 E[9];
    f32x4 zed = {0.f, 0.f, 0.f, 0.f};
#pragma unroll
    for (int i = 0; i < 9; ++i) E[i] = zed;

    for (int cc = 0; cc < C_DIM / 64; ++cc) {
        const int c0 = cc * 64;
        __syncthreads();
        for (int u = tid; u < 288 * 8; u += 256) {
            const int su = u >> 3, un = u & 7;
            const int s = min(s_lo + su, T_DIM - 1);
            const float4* src = (const float4*)(Kb + (size_t)s * C_DIM + c0 + un * 8);
            float4 x = src[0], y = src[1];
            uint4 o; o.x = pk2(x.x, x.y); o.y = pk2(x.z, x.w);
            o.z = pk2(y.x, y.y); o.w = pk2(y.z, y.w);
            *(uint4*)(Kc + su * KROW + un * 8) = o;
        }
        {
            const int su = tid >> 3, un = tid & 7;
            const float4* src = (const float4*)(Qb + (size_t)(t0 + su) * C_DIM + c0 + un * 8);
            float4 x = src[0], y = src[1];
            uint4 o; o.x = pk2(x.x, x.y); o.y = pk2(x.z, x.w);
            o.z = pk2(y.x, y.y); o.w = pk2(y.z, y.w);
            *(uint4*)(Qc + su * KROW + un * 8) = o;
        }
        __syncthreads();
        s16x8 aq[2];
#pragma unroll
        for (int kk = 0; kk < 2; ++kk)
            aq[kk] = *(const s16x8*)(Qc + (th * 16 + ln) * KROW + kk * 32 + g * 8);
#pragma unroll
        for (int i = 0; i < 9; ++i) {
            const int srow2 = (sh * 9 + i) * 16 + ln;
#pragma unroll
            for (int kk = 0; kk < 2; ++kk) {
                s16x8 bk = *(const s16x8*)(Kc + srow2 * KROW + kk * 32 + g * 8);
                E[i] = __builtin_amdgcn_mfma_f32_16x16x32_bf16(aq[kk], bk, E[i], 0, 0, 0);
            }
        }
    }

    const float scale = 0.03125f;
    const int rowb = th * 16 + g * 4;
    float lm[4];
#pragma unroll
    for (int r = 0; r < 4; ++r) lm[r] = -INFINITY;
    const int s_base = s_lo + sh * 144 + ln;
#pragma unroll
    for (int i = 0; i < 9; ++i) {
        const int s = s_base + i * 16;
#pragma unroll
        for (int r = 0; r < 4; ++r) {
            const int t = t0 + rowb + r;
            int d = t - s; d = d < 0 ? -d : d;
            const bool valid = (s <= s_hi) && (d <= m);
            float e = valid ? E[i][r] : -INFINITY;
            E[i][r] = e;
            lm[r] = fmaxf(lm[r], e);
        }
    }
#pragma unroll
    for (int r = 0; r < 4; ++r)
#pragma unroll
        for (int dd = 1; dd < 16; dd <<= 1) lm[r] = fmaxf(lm[r], __shfl_xor(lm[r], dd));
    if (ln == 0) {
#pragma unroll
        for (int r = 0; r < 4; ++r) pmax[sh * 32 + rowb + r] = lm[r];
    }
    __syncthreads();
    float Mr[4], sum[4];
#pragma unroll
    for (int r = 0; r < 4; ++r) {
        Mr[r] = fmaxf(pmax[rowb + r], pmax[32 + rowb + r]) * scale;
        sum[r] = 0.f;
    }
#pragma unroll
    for (int i = 0; i < 9; ++i)
#pragma unroll
        for (int r = 0; r < 4; ++r) {
            float e = __expf(E[i][r] * scale - Mr[r]);
            E[i][r] = e;
            sum[r] += e;
        }
#pragma unroll
    for (int r = 0; r < 4; ++r)
#pragma unroll
        for (int dd = 1; dd < 16; dd <<= 1) sum[r] += __shfl_xor(sum[r], dd);
    if (ln == 0) {
#pragma unroll
        for (int r = 0; r < 4; ++r) psum[sh * 32 + rowb + r] = sum[r];
    }
    __syncthreads();
    float inv[4];
#pragma unroll
    for (int r = 0; r < 4; ++r) inv[r] = 1.0f / (psum[rowb + r] + psum[32 + rowb + r]);
#pragma unroll
    for (int i = 0; i < 9; ++i) {
        const int col = sh * 144 + i * 16 + ln;
#pragma unroll
        for (int r = 0; r < 4; ++r)
            P[(rowb + r) * PROW + col] = (short)f2bf(E[i][r] * inv[r]);
    }
    __syncthreads();

    s16x8 pa[9];
#pragma unroll
    for (int kg = 0; kg < 9; ++kg)
        pa[kg] = *(const s16x8*)(P + (th * 16 + ln) * PROW + kg * 32 + g * 8);

    float maskv[4], rmax[4];
#pragma unroll
    for (int r = 0; r < 4; ++r) {
        maskv[r] = Mask[(size_t)b * T_DIM + t0 + rowb + r];
        rmax[r]  = -INFINITY;
    }

    for (int cc = 0; cc < C_DIM / 64; ++cc) {
        __syncthreads();
        for (int i2 = tid; i2 < 64 * 36; i2 += 256) {
            const int cr = i2 / 36, un = i2 - cr * 36;
            const int sb = min(s_lo + un * 8, T_DIM - 8);
            uint4 x = *(const uint4*)(Vtb + (size_t)(cc * 64 + cr) * T_DIM + sb);
            *(uint4*)(Vl + cr * PROW + un * 8) = x;
        }
        __syncthreads();
#pragma unroll
        for (int nbi = 0; nbi < 2; ++nbi) {
            const int crow = sh * 32 + nbi * 16 + ln;
            f32x4 O = zed;
#pragma unroll
            for (int kg = 0; kg < 9; ++kg) {
                s16x8 bv = *(const s16x8*)(Vl + crow * PROW + kg * 32 + g * 8);
                O = __builtin_amdgcn_mfma_f32_16x16x32_bf16(pa[kg], bv, O, 0, 0, 0);
            }
#pragma unroll
            for (int r = 0; r < 4; ++r)
                rmax[r] = fmaxf(rmax[r], O[r] * maskv[r]);
        }
    }
#pragma unroll
    for (int r = 0; r < 4; ++r)
#pragma unroll
        for (int dd = 1; dd < 16; dd <<= 1) rmax[r] = fmaxf(rmax[r], __shfl_xor(rmax[r], dd));
    if (ln == 0) {
#pragma unroll
        for (int r = 0; r < 4; ++r) red[sh * 32 + rowb + r] = rmax[r];
    }
    __syncthreads();
    if (tid < 32)
        wsrow[(size_t)b * T_DIM + t0 + tid] = fmaxf(red[tid], red[32 + tid]);
}

// out[b] = sum_t ws[b][t]
__global__ void reduce_b(const float* __restrict__ ws, float* __restrict__ out)
{
    const int b = blockIdx.x;
    float s = 0.f;
    for (int t = threadIdx.x; t < T_DIM; t += 256) s += ws[(size_t)b * T_DIM + t];
#pragma unroll
    for (int dd = 32; dd > 0; dd >>= 1) s += __shfl_xor(s, dd);
    __shared__ float acc[4];
    if ((threadIdx.x & 63) == 0) acc[threadIdx.x >> 6] = s;
    __syncthreads();
    if (threadIdx.x == 0) out[b] = acc[0] + acc[1] + acc[2] + acc[3];
}

extern "C" void kernel_launch(void* const* d_in, const int* in_sizes, int n_in,
                              void* d_out, int out_size, void* d_ws, size_t ws_size,
                              hipStream_t stream)
{
    const float* Q    = (const float*)d_in[0];
    const float* K    = (const float*)d_in[1];
    const float* V    = (const float*)d_in[2];
    const float* Mask = (const float*)d_in[3];
    const int*   m    = (const int*)d_in[4];
    float* out = (float*)d_out;

    const size_t frag_bytes = (size_t)B_DIM * T_DIM * C_DIM * 2;   // 33,554,432 per tensor
    const size_t need_main  = 2 * frag_bytes + (size_t)B_DIM * T_DIM * 4;
    const size_t need_fb    = frag_bytes + (size_t)B_DIM * T_DIM * 4;

    if (ws_size >= need_main) {
        unsigned short* Kt  = (unsigned short*)d_ws;
        unsigned short* Vtt = (unsigned short*)((char*)d_ws + frag_bytes);
        float* wsrow = (float*)((char*)d_ws + 2 * frag_bytes);
        tile_k<<<dim3(128, B_DIM), 256, 0, stream>>>(K, Kt);
        transpose_vx<<<dim3(T_DIM / 64, C_DIM / 64, B_DIM), 256, 0, stream>>>(V, Vtt, 1);
        attn_band_tiled<<<dim3((T_DIM / TB) * B_DIM), 256, 0, stream>>>(Q, Kt, Vtt, Mask, m, wsrow);
        reduce_b<<<B_DIM, 256, 0, stream>>>(wsrow, out);
    } else {
        unsigned short* Vt = (unsigned short*)d_ws;
        float* wsrow = (float*)((char*)d_ws + frag_bytes);
        transpose_vx<<<dim3(T_DIM / 64, C_DIM / 64, B_DIM), 256, 0, stream>>>(V, Vt, 0);
        attn_band_mfma<<<dim3((T_DIM / TB) * B_DIM), 256, 0, stream>>>(Q, K, Vt, Mask, m, wsrow);
        reduce_b<<<B_DIM, 256, 0, stream>>>(wsrow, out);
    }
}

// Round 6
// 135.225 us; speedup vs baseline: 1.4494x; 1.0645x over previous
//
#include <hip/hip_runtime.h>
#include <math.h>

#define T_DIM 2048
#define C_DIM 1024
#define B_DIM 8
#define TB    32
#define KROW  72      // bf16 elems per Kc/Qc row (64 + 8 pad)  [fallback kernel]
#define PROW  296     // bf16 elems per P row (288 + 8 pad)

typedef float f32x4 __attribute__((ext_vector_type(4)));
typedef short s16x8 __attribute__((ext_vector_type(8)));

__device__ __forceinline__ unsigned short f2bf(float x) {
    union { float f; unsigned u; } v; v.f = x;
    unsigned r = v.u + 0x7fffu + ((v.u >> 16) & 1u);
    return (unsigned short)(r >> 16);
}
__device__ __forceinline__ unsigned pk2(float a, float b) {
    return (unsigned)f2bf(a) | ((unsigned)f2bf(b) << 16);
}

// ============ pre-pass A: Q,K f32 -> fragment-major bf16 Xt[b][tile][kk][lane][8] ============
// elem = X[b][tile*16+(l&15)][kk*32+(l>>4)*8+j].  No LDS, no barriers.
// Per wave-instr: reads 16 rows x 128B (full lines, each byte once); writes 1KB contiguous.
__global__ __launch_bounds__(256)
void tile_qk(const float* __restrict__ Q, const float* __restrict__ K,
             unsigned short* __restrict__ Qt, unsigned short* __restrict__ Kt)
{
    const int bx   = blockIdx.x;            // 0..255
    const int tile = bx & 127;
    const float* src = (bx < 128) ? Q : K;
    unsigned short* dst = (bx < 128) ? Qt : Kt;
    const int b    = blockIdx.y;
    const int tid  = threadIdx.x;
    const int w = tid >> 6, l = tid & 63, g = l >> 4, ln = l & 15;
    const float* src_row = src + (size_t)(b * T_DIM + tile * 16 + ln) * C_DIM;
#pragma unroll
    for (int kki = 0; kki < 8; ++kki) {
        const int kk = kki * 4 + w;
        const float4* p = (const float4*)(src_row + kk * 32 + g * 8);
        float4 x = p[0], y = p[1];
        uint4 o;
        o.x = pk2(x.x, x.y); o.y = pk2(x.z, x.w);
        o.z = pk2(y.x, y.y); o.w = pk2(y.z, y.w);
        *(uint4*)(dst + (size_t)(((b * 128 + tile) * 32 + kk) * 64 + l) * 8) = o;
    }
}

// ============ pre-pass B: V f32 -> bf16, fragment-major Vtt OR row-major Vt ============
// frag_mode=1: Vtt[b][ct][sg][lane][8], elem = V[b][sg*32+(l>>4)*8+j][ct*16+(l&15)]
// frag_mode=0: Vt[b][c][t] row-major (fallback path layout)
__global__ __launch_bounds__(256)
void transpose_vx(const float* __restrict__ V, unsigned short* __restrict__ out,
                  int frag_mode)
{
    __shared__ float buf[64 * 67];
    const int t0 = blockIdx.x * 64;
    const int c0 = blockIdx.y * 64;
    const int b  = blockIdx.z;
    const float* Vb = V + (size_t)b * T_DIM * C_DIM;

    for (int i = threadIdx.x; i < 64 * 64; i += 256) {
        const int r = i >> 6, c = i & 63;
        buf[r * 67 + c] = Vb[(size_t)(t0 + r) * C_DIM + c0 + c];
    }
    __syncthreads();
    const int t8 = threadIdx.x & 7;   // 8-t segment
    const int cl = threadIdx.x >> 3;  // 0..31
#pragma unroll
    for (int half = 0; half < 2; ++half) {
        const int c_loc = cl + half * 32;
        float v[8];
#pragma unroll
        for (int j = 0; j < 8; ++j) v[j] = buf[(t8 * 8 + j) * 67 + c_loc];
        uint4 o;
        o.x = pk2(v[0], v[1]); o.y = pk2(v[2], v[3]);
        o.z = pk2(v[4], v[5]); o.w = pk2(v[6], v[7]);
        if (frag_mode) {
            const int ct = (c0 + c_loc) >> 4, lnv = c_loc & 15;
            const int g = t8 & 3, sg = (t0 >> 5) + (t8 >> 2);
            *(uint4*)(out + (size_t)(((b * 64 + ct) * 64 + sg) * 64 + g * 16 + lnv) * 8) = o;
        } else {
            *(uint4*)(out + (size_t)(b * C_DIM + c0 + c_loc) * T_DIM + t0 + t8 * 8) = o;
        }
    }
}

// ============ banded attention: ALL operands fragment-major (coalesced 1KB wave loads) ============
// 256 thr = 4 waves (th = t-half of 32-row tile, sh = s-half / c-split).  [verified r2/r3]
__global__ __launch_bounds__(256, 2)
void attn_band_tiled(const unsigned short* __restrict__ Qt,
                     const unsigned short* __restrict__ Kt,
                     const unsigned short* __restrict__ Vtt,
                     const float* __restrict__ Mask, const int* __restrict__ m_ptr,
                     float* __restrict__ wsrow)
{
    __shared__ short P[32 * PROW];            // 18,944 B
    __shared__ float pmax[64], psum[64], red[64];

    // XCD-bijective swizzle: each XCD owns one batch's contiguous t-range
    const int h = blockIdx.x;
    const int logical = (h & 7) * 64 + (h >> 3);
    const int b  = logical >> 6;
    const int t0 = (logical & 63) * TB;

    const int tid = threadIdx.x;
    const int w = tid >> 6, lane = tid & 63, g = lane >> 4, ln = lane & 15;
    const int th = w >> 1, sh = w & 1;
    const int m  = m_ptr[0];

    const int s_lo = max(0, t0 - m);
    const int s_hi = min(T_DIM - 1, t0 + TB - 1 + m);
    const int sg0  = s_lo >> 5;               // 32-aligned by construction
    const int tq   = (t0 >> 4) + th;

    const unsigned short* Qtb = Qt  + (size_t)b * 128 * 32 * 512;
    const unsigned short* Ktb = Kt  + (size_t)b * 128 * 32 * 512;
    const unsigned short* Vtb = Vtt + (size_t)b * 64 * 64 * 512;

    int stg[9];
#pragma unroll
    for (int i = 0; i < 9; ++i) stg[i] = min(sg0 * 2 + sh * 9 + i, 127);

    // ---- phase 1: E = Q.K^T, fragments streamed from global ----
    f32x4 E[9];
    f32x4 zed = {0.f, 0.f, 0.f, 0.f};
#pragma unroll
    for (int i = 0; i < 9; ++i) E[i] = zed;

#pragma unroll 4
    for (int kk = 0; kk < 32; ++kk) {
        s16x8 aq = *(const s16x8*)(Qtb + (size_t)((tq * 32 + kk) * 64 + lane) * 8);
#pragma unroll
        for (int i = 0; i < 9; ++i) {
            s16x8 bk = *(const s16x8*)(Ktb + (size_t)((stg[i] * 32 + kk) * 64 + lane) * 8);
            E[i] = __builtin_amdgcn_mfma_f32_16x16x32_bf16(aq, bk, E[i], 0, 0, 0);
        }
    }

    // ---- phase 2: exact softmax (cross-wave over the two s-halves) ----
    const float scale = 0.03125f;   // 1/sqrt(1024)
    const int rowb = th * 16 + g * 4;
    float lm[4];
#pragma unroll
    for (int r = 0; r < 4; ++r) lm[r] = -INFINITY;
    const int s_base = s_lo + sh * 144 + ln;
#pragma unroll
    for (int i = 0; i < 9; ++i) {
        const int s = s_base + i * 16;
#pragma unroll
        for (int r = 0; r < 4; ++r) {
            const int t = t0 + rowb + r;
            int d = t - s; d = d < 0 ? -d : d;
            const bool valid = (s <= s_hi) && (d <= m);
            float e = valid ? E[i][r] : -INFINITY;
            E[i][r] = e;
            lm[r] = fmaxf(lm[r], e);
        }
    }
#pragma unroll
    for (int r = 0; r < 4; ++r)
#pragma unroll
        for (int dd = 1; dd < 16; dd <<= 1) lm[r] = fmaxf(lm[r], __shfl_xor(lm[r], dd));
    if (ln == 0) {
#pragma unroll
        for (int r = 0; r < 4; ++r) pmax[sh * 32 + rowb + r] = lm[r];
    }
    __syncthreads();
    float Mr[4], sum[4];
#pragma unroll
    for (int r = 0; r < 4; ++r) {
        Mr[r] = fmaxf(pmax[rowb + r], pmax[32 + rowb + r]) * scale;
        sum[r] = 0.f;
    }
#pragma unroll
    for (int i = 0; i < 9; ++i)
#pragma unroll
        for (int r = 0; r < 4; ++r) {
            float e = __expf(E[i][r] * scale - Mr[r]);   // -inf -> 0 exactly
            E[i][r] = e;
            sum[r] += e;
        }
#pragma unroll
    for (int r = 0; r < 4; ++r)
#pragma unroll
        for (int dd = 1; dd < 16; dd <<= 1) sum[r] += __shfl_xor(sum[r], dd);
    if (ln == 0) {
#pragma unroll
        for (int r = 0; r < 4; ++r) psum[sh * 32 + rowb + r] = sum[r];
    }
    __syncthreads();
    float inv[4];
#pragma unroll
    for (int r = 0; r < 4; ++r) inv[r] = 1.0f / (psum[rowb + r] + psum[32 + rowb + r]);
#pragma unroll
    for (int i = 0; i < 9; ++i) {
        const int col = sh * 144 + i * 16 + ln;
#pragma unroll
        for (int r = 0; r < 4; ++r)
            P[(rowb + r) * PROW + col] = (short)f2bf(E[i][r] * inv[r]);
    }
    __syncthreads();

    // ---- phase 3: O = P @ V, V fragments direct from global; fold masked row-max ----
    s16x8 pa[9];
#pragma unroll
    for (int kg = 0; kg < 9; ++kg)
        pa[kg] = *(const s16x8*)(P + (th * 16 + ln) * PROW + kg * 32 + g * 8);

    int sgc[9];
#pragma unroll
    for (int kg = 0; kg < 9; ++kg) sgc[kg] = min(sg0 + kg, 63);

    float maskv[4], rmax[4];
#pragma unroll
    for (int r = 0; r < 4; ++r) {
        maskv[r] = Mask[(size_t)b * T_DIM + t0 + rowb + r];
        rmax[r]  = -INFINITY;
    }

    for (int q = 0; q < 16; ++q) {
        const int ct0 = q * 4 + sh * 2;
        f32x4 O0 = zed, O1 = zed;
#pragma unroll
        for (int kg = 0; kg < 9; ++kg) {
            s16x8 bv0 = *(const s16x8*)(Vtb + (size_t)(((ct0    ) * 64 + sgc[kg]) * 64 + lane) * 8);
            s16x8 bv1 = *(const s16x8*)(Vtb + (size_t)(((ct0 + 1) * 64 + sgc[kg]) * 64 + lane) * 8);
            O0 = __builtin_amdgcn_mfma_f32_16x16x32_bf16(pa[kg], bv0, O0, 0, 0, 0);
            O1 = __builtin_amdgcn_mfma_f32_16x16x32_bf16(pa[kg], bv1, O1, 0, 0, 0);
        }
#pragma unroll
        for (int r = 0; r < 4; ++r) {
            rmax[r] = fmaxf(rmax[r], O0[r] * maskv[r]);
            rmax[r] = fmaxf(rmax[r], O1[r] * maskv[r]);
        }
    }
#pragma unroll
    for (int r = 0; r < 4; ++r)
#pragma unroll
        for (int dd = 1; dd < 16; dd <<= 1) rmax[r] = fmaxf(rmax[r], __shfl_xor(rmax[r], dd));
    if (ln == 0) {
#pragma unroll
        for (int r = 0; r < 4; ++r) red[sh * 32 + rowb + r] = rmax[r];
    }
    __syncthreads();
    if (tid < 32)
        wsrow[(size_t)b * T_DIM + t0 + tid] = fmaxf(red[tid], red[32 + tid]);
}

// ============ fallback (round-1, verified): K/V staged per block, Vt row-major ============
__global__ __launch_bounds__(256, 2)
void attn_band_mfma(const float* __restrict__ Q, const float* __restrict__ K,
                    const unsigned short* __restrict__ Vt,
                    const float* __restrict__ Mask, const int* __restrict__ m_ptr,
                    float* __restrict__ wsrow)
{
    __shared__ __align__(16) char smem_raw[57600];
    short* SM = (short*)smem_raw;
    short* Kc = SM;
    short* Qc = SM + 288 * KROW;
    short* P  = SM;
    short* Vl = SM + 32 * PROW;
    float* pmax = (float*)(smem_raw + 56832);
    float* psum = pmax + 64;
    float* red  = psum + 64;

    const int h = blockIdx.x;
    const int logical = (h & 7) * 64 + (h >> 3);
    const int b  = logical >> 6;
    const int t0 = (logical & 63) * TB;

    const int tid = threadIdx.x;
    const int w = tid >> 6, lane = tid & 63, g = lane >> 4, ln = lane & 15;
    const int th = w >> 1, sh = w & 1;
    const int m  = m_ptr[0];

    const int s_lo = max(0, t0 - m);
    const int s_hi = min(T_DIM - 1, t0 + TB - 1 + m);

    const float* Qb = Q + (size_t)b * T_DIM * C_DIM;
    const float* Kb = K + (size_t)b * T_DIM * C_DIM;
    const unsigned short* Vtb = Vt + (size_t)b * C_DIM * T_DIM;

    f32x4 E[9];
    f32x4 zed = {0.f, 0.f, 0.f, 0.f};
#pragma unroll
    for (int i = 0; i < 9; ++i) E[i] = zed;

    for (int cc = 0; cc < C_DIM / 64; ++cc) {
        const int c0 = cc * 64;
        __syncthreads();
        for (int u = tid; u < 288 * 8; u += 256) {
            const int su = u >> 3, un = u & 7;
            const int s = min(s_lo + su, T_DIM - 1);
            const float4* src = (const float4*)(Kb + (size_t)s * C_DIM + c0 + un * 8);
            float4 x = src[0], y = src[1];
            uint4 o; o.x = pk2(x.x, x.y); o.y = pk2(x.z, x.w);
            o.z = pk2(y.x, y.y); o.w = pk2(y.z, y.w);
            *(uint4*)(Kc + su * KROW + un * 8) = o;
        }
        {
            const int su = tid >> 3, un = tid & 7;
            const float4* src = (const float4*)(Qb + (size_t)(t0 + su) * C_DIM + c0 + un * 8);
            float4 x = src[0], y = src[1];
            uint4 o; o.x = pk2(x.x, x.y); o.y = pk2(x.z, x.w);
            o.z = pk2(y.x, y.y); o.w = pk2(y.z, y.w);
            *(uint4*)(Qc + su * KROW + un * 8) = o;
        }
        __syncthreads();
        s16x8 aq[2];
#pragma unroll
        for (int kk = 0; kk < 2; ++kk)
            aq[kk] = *(const s16x8*)(Qc + (th * 16 + ln) * KROW + kk * 32 + g * 8);
#pragma unroll
        for (int i = 0; i < 9; ++i) {
            const int srow2 = (sh * 9 + i) * 16 + ln;
#pragma unroll
            for (int kk = 0; kk < 2; ++kk) {
                s16x8 bk = *(const s16x8*)(Kc + srow2 * KROW + kk * 32 + g * 8);
                E[i] = __builtin_amdgcn_mfma_f32_16x16x32_bf16(aq[kk], bk, E[i], 0, 0, 0);
            }
        }
    }

    const float scale = 0.03125f;
    const int rowb = th * 16 + g * 4;
    float lm[4];
#pragma unroll
    for (int r = 0; r < 4; ++r) lm[r] = -INFINITY;
    const int s_base = s_lo + sh * 144 + ln;
#pragma unroll
    for (int i = 0; i < 9; ++i) {
        const int s = s_base + i * 16;
#pragma unroll
        for (int r = 0; r < 4; ++r) {
            const int t = t0 + rowb + r;
            int d = t - s; d = d < 0 ? -d : d;
            const bool valid = (s <= s_hi) && (d <= m);
            float e = valid ? E[i][r] : -INFINITY;
            E[i][r] = e;
            lm[r] = fmaxf(lm[r], e);
        }
    }
#pragma unroll
    for (int r = 0; r < 4; ++r)
#pragma unroll
        for (int dd = 1; dd < 16; dd <<= 1) lm[r] = fmaxf(lm[r], __shfl_xor(lm[r], dd));
    if (ln == 0) {
#pragma unroll
        for (int r = 0; r < 4; ++r) pmax[sh * 32 + rowb + r] = lm[r];
    }
    __syncthreads();
    float Mr[4], sum[4];
#pragma unroll
    for (int r = 0; r < 4; ++r) {
        Mr[r] = fmaxf(pmax[rowb + r], pmax[32 + rowb + r]) * scale;
        sum[r] = 0.f;
    }
#pragma unroll
    for (int i = 0; i < 9; ++i)
#pragma unroll
        for (int r = 0; r < 4; ++r) {
            float e = __expf(E[i][r] * scale - Mr[r]);
            E[i][r] = e;
            sum[r] += e;
        }
#pragma unroll
    for (int r = 0; r < 4; ++r)
#pragma unroll
        for (int dd = 1; dd < 16; dd <<= 1) sum[r] += __shfl_xor(sum[r], dd);
    if (ln == 0) {
#pragma unroll
        for (int r = 0; r < 4; ++r) psum[sh * 32 + rowb + r] = sum[r];
    }
    __syncthreads();
    float inv[4];
#pragma unroll
    for (int r = 0; r < 4; ++r) inv[r] = 1.0f / (psum[rowb + r] + psum[32 + rowb + r]);
#pragma unroll
    for (int i = 0; i < 9; ++i) {
        const int col = sh * 144 + i * 16 + ln;
#pragma unroll
        for (int r = 0; r < 4; ++r)
            P[(rowb + r) * PROW + col] = (short)f2bf(E[i][r] * inv[r]);
    }
    __syncthreads();

    s16x8 pa[9];
#pragma unroll
    for (int kg = 0; kg < 9; ++kg)
        pa[kg] = *(const s16x8*)(P + (th * 16 + ln) * PROW + kg * 32 + g * 8);

    float maskv[4], rmax[4];
#pragma unroll
    for (int r = 0; r < 4; ++r) {
        maskv[r] = Mask[(size_t)b * T_DIM + t0 + rowb + r];
        rmax[r]  = -INFINITY;
    }

    for (int cc = 0; cc < C_DIM / 64; ++cc) {
        __syncthreads();
        for (int i2 = tid; i2 < 64 * 36; i2 += 256) {
            const int cr = i2 / 36, un = i2 - cr * 36;
            const int sb = min(s_lo + un * 8, T_DIM - 8);
            uint4 x = *(const uint4*)(Vtb + (size_t)(cc * 64 + cr) * T_DIM + sb);
            *(uint4*)(Vl + cr * PROW + un * 8) = x;
        }
        __syncthreads();
#pragma unroll
        for (int nbi = 0; nbi < 2; ++nbi) {
            const int crow = sh * 32 + nbi * 16 + ln;
            f32x4 O = zed;
#pragma unroll
            for (int kg = 0; kg < 9; ++kg) {
                s16x8 bv = *(const s16x8*)(Vl + crow * PROW + kg * 32 + g * 8);
                O = __builtin_amdgcn_mfma_f32_16x16x32_bf16(pa[kg], bv, O, 0, 0, 0);
            }
#pragma unroll
            for (int r = 0; r < 4; ++r)
                rmax[r] = fmaxf(rmax[r], O[r] * maskv[r]);
        }
    }
#pragma unroll
    for (int r = 0; r < 4; ++r)
#pragma unroll
        for (int dd = 1; dd < 16; dd <<= 1) rmax[r] = fmaxf(rmax[r], __shfl_xor(rmax[r], dd));
    if (ln == 0) {
#pragma unroll
        for (int r = 0; r < 4; ++r) red[sh * 32 + rowb + r] = rmax[r];
    }
    __syncthreads();
    if (tid < 32)
        wsrow[(size_t)b * T_DIM + t0 + tid] = fmaxf(red[tid], red[32 + tid]);
}

// out[b] = sum_t ws[b][t]
__global__ void reduce_b(const float* __restrict__ ws, float* __restrict__ out)
{
    const int b = blockIdx.x;
    float s = 0.f;
    for (int t = threadIdx.x; t < T_DIM; t += 256) s += ws[(size_t)b * T_DIM + t];
#pragma unroll
    for (int dd = 32; dd > 0; dd >>= 1) s += __shfl_xor(s, dd);
    __shared__ float acc[4];
    if ((threadIdx.x & 63) == 0) acc[threadIdx.x >> 6] = s;
    __syncthreads();
    if (threadIdx.x == 0) out[b] = acc[0] + acc[1] + acc[2] + acc[3];
}

extern "C" void kernel_launch(void* const* d_in, const int* in_sizes, int n_in,
                              void* d_out, int out_size, void* d_ws, size_t ws_size,
                              hipStream_t stream)
{
    const float* Q    = (const float*)d_in[0];
    const float* K    = (const float*)d_in[1];
    const float* V    = (const float*)d_in[2];
    const float* Mask = (const float*)d_in[3];
    const int*   m    = (const int*)d_in[4];
    float* out = (float*)d_out;

    const size_t frag_bytes = (size_t)B_DIM * T_DIM * C_DIM * 2;   // 33,554,432 per tensor
    const size_t need_main  = 3 * frag_bytes + (size_t)B_DIM * T_DIM * 4;
    const size_t need_fb    = frag_bytes + (size_t)B_DIM * T_DIM * 4;

    if (ws_size >= need_main) {
        unsigned short* Qt  = (unsigned short*)d_ws;
        unsigned short* Kt  = (unsigned short*)((char*)d_ws + frag_bytes);
        unsigned short* Vtt = (unsigned short*)((char*)d_ws + 2 * frag_bytes);
        float* wsrow = (float*)((char*)d_ws + 3 * frag_bytes);
        tile_qk<<<dim3(256, B_DIM), 256, 0, stream>>>(Q, K, Qt, Kt);
        transpose_vx<<<dim3(T_DIM / 64, C_DIM / 64, B_DIM), 256, 0, stream>>>(V, Vtt, 1);
        attn_band_tiled<<<dim3((T_DIM / TB) * B_DIM), 256, 0, stream>>>(Qt, Kt, Vtt, Mask, m, wsrow);
        reduce_b<<<B_DIM, 256, 0, stream>>>(wsrow, out);
    } else {
        unsigned short* Vt = (unsigned short*)d_ws;
        float* wsrow = (float*)((char*)d_ws + frag_bytes);
        transpose_vx<<<dim3(T_DIM / 64, C_DIM / 64, B_DIM), 256, 0, stream>>>(V, Vt, 0);
        attn_band_mfma<<<dim3((T_DIM / TB) * B_DIM), 256, 0, stream>>>(Q, K, Vt, Mask, m, wsrow);
        reduce_b<<<B_DIM, 256, 0, stream>>>(wsrow, out);
    }
}

// Round 7
// 134.420 us; speedup vs baseline: 1.4581x; 1.0060x over previous
//
#include <hip/hip_runtime.h>
#include <math.h>

#define T_DIM 2048
#define C_DIM 1024
#define B_DIM 8
#define TB    32
#define KROW  72      // bf16 elems per Kc/Qc row (64 + 8 pad)  [fallback kernel]
#define PROW  296     // bf16 elems per P row (288 + 8 pad)

typedef float f32x4 __attribute__((ext_vector_type(4)));
typedef short s16x8 __attribute__((ext_vector_type(8)));

__device__ __forceinline__ unsigned short f2bf(float x) {
    union { float f; unsigned u; } v; v.f = x;
    unsigned r = v.u + 0x7fffu + ((v.u >> 16) & 1u);
    return (unsigned short)(r >> 16);
}
__device__ __forceinline__ unsigned pk2(float a, float b) {
    return (unsigned)f2bf(a) | ((unsigned)f2bf(b) << 16);
}

// ============ pre-pass A: Q,K f32 -> fragment-major bf16 Xt[b][tile][kk][lane][8] ============
__global__ __launch_bounds__(256)
void tile_qk(const float* __restrict__ Q, const float* __restrict__ K,
             unsigned short* __restrict__ Qt, unsigned short* __restrict__ Kt)
{
    const int bx   = blockIdx.x;            // 0..255
    const int tile = bx & 127;
    const float* src = (bx < 128) ? Q : K;
    unsigned short* dst = (bx < 128) ? Qt : Kt;
    const int b    = blockIdx.y;
    const int tid  = threadIdx.x;
    const int w = tid >> 6, l = tid & 63, g = l >> 4, ln = l & 15;
    const float* src_row = src + (size_t)(b * T_DIM + tile * 16 + ln) * C_DIM;
#pragma unroll
    for (int kki = 0; kki < 8; ++kki) {
        const int kk = kki * 4 + w;
        const float4* p = (const float4*)(src_row + kk * 32 + g * 8);
        float4 x = p[0], y = p[1];
        uint4 o;
        o.x = pk2(x.x, x.y); o.y = pk2(x.z, x.w);
        o.z = pk2(y.x, y.y); o.w = pk2(y.z, y.w);
        *(uint4*)(dst + (size_t)(((b * 128 + tile) * 32 + kk) * 64 + l) * 8) = o;
    }
}

// ============ pre-pass B: V f32 -> bf16, fragment-major Vtt OR row-major Vt ============
__global__ __launch_bounds__(256)
void transpose_vx(const float* __restrict__ V, unsigned short* __restrict__ out,
                  int frag_mode)
{
    __shared__ float buf[64 * 67];
    const int t0 = blockIdx.x * 64;
    const int c0 = blockIdx.y * 64;
    const int b  = blockIdx.z;
    const float* Vb = V + (size_t)b * T_DIM * C_DIM;

    for (int i = threadIdx.x; i < 64 * 64; i += 256) {
        const int r = i >> 6, c = i & 63;
        buf[r * 67 + c] = Vb[(size_t)(t0 + r) * C_DIM + c0 + c];
    }
    __syncthreads();
    const int t8 = threadIdx.x & 7;   // 8-t segment
    const int cl = threadIdx.x >> 3;  // 0..31
#pragma unroll
    for (int half = 0; half < 2; ++half) {
        const int c_loc = cl + half * 32;
        float v[8];
#pragma unroll
        for (int j = 0; j < 8; ++j) v[j] = buf[(t8 * 8 + j) * 67 + c_loc];
        uint4 o;
        o.x = pk2(v[0], v[1]); o.y = pk2(v[2], v[3]);
        o.z = pk2(v[4], v[5]); o.w = pk2(v[6], v[7]);
        if (frag_mode) {
            const int ct = (c0 + c_loc) >> 4, lnv = c_loc & 15;
            const int g = t8 & 3, sg = (t0 >> 5) + (t8 >> 2);
            *(uint4*)(out + (size_t)(((b * 64 + ct) * 64 + sg) * 64 + g * 16 + lnv) * 8) = o;
        } else {
            *(uint4*)(out + (size_t)(b * C_DIM + c0 + c_loc) * T_DIM + t0 + t8 * 8) = o;
        }
    }
}

// ============ banded attention: fragment-major operands + register prefetch rings ============
// 256 thr = 4 waves (th = t-half of 32-row tile, sh = s-half / c-split).
__global__ __launch_bounds__(256, 2)
void attn_band_tiled(const unsigned short* __restrict__ Qt,
                     const unsigned short* __restrict__ Kt,
                     const unsigned short* __restrict__ Vtt,
                     const float* __restrict__ Mask, const int* __restrict__ m_ptr,
                     float* __restrict__ wsrow)
{
    __shared__ short P[32 * PROW];            // 18,944 B
    __shared__ float pmax[64], psum[64], red[64];

    // XCD-bijective swizzle: each XCD owns one batch's contiguous t-range
    const int h = blockIdx.x;
    const int logical = (h & 7) * 64 + (h >> 3);
    const int b  = logical >> 6;
    const int t0 = (logical & 63) * TB;

    const int tid = threadIdx.x;
    const int w = tid >> 6, lane = tid & 63, g = lane >> 4, ln = lane & 15;
    const int th = w >> 1, sh = w & 1;
    const int m  = m_ptr[0];

    const int s_lo = max(0, t0 - m);
    const int s_hi = min(T_DIM - 1, t0 + TB - 1 + m);
    const int sg0  = s_lo >> 5;               // 32-aligned by construction
    const int tq   = (t0 >> 4) + th;

    const unsigned short* Qtb = Qt  + (size_t)b * 128 * 32 * 512;
    const unsigned short* Ktb = Kt  + (size_t)b * 128 * 32 * 512;
    const unsigned short* Vtb = Vtt + (size_t)b * 64 * 64 * 512;

    int stg[9];
#pragma unroll
    for (int i = 0; i < 9; ++i) stg[i] = min(sg0 * 2 + sh * 9 + i, 127);

    // ---- phase 1: E = Q.K^T, depth-1 register prefetch ring ----
    f32x4 E[9];
    f32x4 zed = {0.f, 0.f, 0.f, 0.f};
#pragma unroll
    for (int i = 0; i < 9; ++i) E[i] = zed;

    s16x8 aqr[2];
    s16x8 bkr[2][9];
    aqr[0] = *(const s16x8*)(Qtb + (size_t)((tq * 32 + 0) * 64 + lane) * 8);
#pragma unroll
    for (int i = 0; i < 9; ++i)
        bkr[0][i] = *(const s16x8*)(Ktb + (size_t)((stg[i] * 32 + 0) * 64 + lane) * 8);

#pragma unroll 2
    for (int kk = 0; kk < 32; ++kk) {
        const int cur = kk & 1, nxt = cur ^ 1;
        const int kn = (kk < 31) ? kk + 1 : 31;     // branchless tail (redundant reload)
        aqr[nxt] = *(const s16x8*)(Qtb + (size_t)((tq * 32 + kn) * 64 + lane) * 8);
#pragma unroll
        for (int i = 0; i < 9; ++i)
            bkr[nxt][i] = *(const s16x8*)(Ktb + (size_t)((stg[i] * 32 + kn) * 64 + lane) * 8);
#pragma unroll
        for (int i = 0; i < 9; ++i)
            E[i] = __builtin_amdgcn_mfma_f32_16x16x32_bf16(aqr[cur], bkr[cur][i], E[i], 0, 0, 0);
    }

    // ---- phase 2: exact softmax (cross-wave over the two s-halves) ----
    const float scale = 0.03125f;   // 1/sqrt(1024)
    const int rowb = th * 16 + g * 4;
    float lm[4];
#pragma unroll
    for (int r = 0; r < 4; ++r) lm[r] = -INFINITY;
    const int s_base = s_lo + sh * 144 + ln;
#pragma unroll
    for (int i = 0; i < 9; ++i) {
        const int s = s_base + i * 16;
#pragma unroll
        for (int r = 0; r < 4; ++r) {
            const int t = t0 + rowb + r;
            int d = t - s; d = d < 0 ? -d : d;
            const bool valid = (s <= s_hi) && (d <= m);
            float e = valid ? E[i][r] : -INFINITY;
            E[i][r] = e;
            lm[r] = fmaxf(lm[r], e);
        }
    }
#pragma unroll
    for (int r = 0; r < 4; ++r)
#pragma unroll
        for (int dd = 1; dd < 16; dd <<= 1) lm[r] = fmaxf(lm[r], __shfl_xor(lm[r], dd));
    if (ln == 0) {
#pragma unroll
        for (int r = 0; r < 4; ++r) pmax[sh * 32 + rowb + r] = lm[r];
    }
    __syncthreads();
    float Mr[4], sum[4];
#pragma unroll
    for (int r = 0; r < 4; ++r) {
        Mr[r] = fmaxf(pmax[rowb + r], pmax[32 + rowb + r]) * scale;
        sum[r] = 0.f;
    }
#pragma unroll
    for (int i = 0; i < 9; ++i)
#pragma unroll
        for (int r = 0; r < 4; ++r) {
            float e = __expf(E[i][r] * scale - Mr[r]);   // -inf -> 0 exactly
            E[i][r] = e;
            sum[r] += e;
        }
#pragma unroll
    for (int r = 0; r < 4; ++r)
#pragma unroll
        for (int dd = 1; dd < 16; dd <<= 1) sum[r] += __shfl_xor(sum[r], dd);
    if (ln == 0) {
#pragma unroll
        for (int r = 0; r < 4; ++r) psum[sh * 32 + rowb + r] = sum[r];
    }
    __syncthreads();
    float inv[4];
#pragma unroll
    for (int r = 0; r < 4; ++r) inv[r] = 1.0f / (psum[rowb + r] + psum[32 + rowb + r]);
#pragma unroll
    for (int i = 0; i < 9; ++i) {
        const int col = sh * 144 + i * 16 + ln;
#pragma unroll
        for (int r = 0; r < 4; ++r)
            P[(rowb + r) * PROW + col] = (short)f2bf(E[i][r] * inv[r]);
    }
    __syncthreads();

    // ---- phase 3: O = P @ V, ct-blocks of 8, kg-outer, depth-1 ring ----
    s16x8 pa[9];
#pragma unroll
    for (int kg = 0; kg < 9; ++kg)
        pa[kg] = *(const s16x8*)(P + (th * 16 + ln) * PROW + kg * 32 + g * 8);

    int sgc[9];
#pragma unroll
    for (int kg = 0; kg < 9; ++kg) sgc[kg] = min(sg0 + kg, 63);

    float maskv[4], rmax[4];
#pragma unroll
    for (int r = 0; r < 4; ++r) {
        maskv[r] = Mask[(size_t)b * T_DIM + t0 + rowb + r];
        rmax[r]  = -INFINITY;
    }

    for (int blk = 0; blk < 4; ++blk) {
        const int ctb = sh * 32 + blk * 8;    // contiguous 8 ct per wave-block
        f32x4 O[8];
#pragma unroll
        for (int j = 0; j < 8; ++j) O[j] = zed;

        s16x8 bvr[2][8];
#pragma unroll
        for (int j = 0; j < 8; ++j)
            bvr[0][j] = *(const s16x8*)(Vtb + (size_t)(((ctb + j) * 64 + sgc[0]) * 64 + lane) * 8);

#pragma unroll
        for (int kg = 0; kg < 9; ++kg) {
            const int cur = kg & 1, nxt = cur ^ 1;
            const int kn = (kg < 8) ? kg + 1 : 8;   // branchless tail
#pragma unroll
            for (int j = 0; j < 8; ++j)
                bvr[nxt][j] = *(const s16x8*)(Vtb + (size_t)(((ctb + j) * 64 + sgc[kn]) * 64 + lane) * 8);
#pragma unroll
            for (int j = 0; j < 8; ++j)
                O[j] = __builtin_amdgcn_mfma_f32_16x16x32_bf16(pa[kg], bvr[cur][j], O[j], 0, 0, 0);
        }
#pragma unroll
        for (int j = 0; j < 8; ++j)
#pragma unroll
            for (int r = 0; r < 4; ++r)
                rmax[r] = fmaxf(rmax[r], O[j][r] * maskv[r]);
    }
#pragma unroll
    for (int r = 0; r < 4; ++r)
#pragma unroll
        for (int dd = 1; dd < 16; dd <<= 1) rmax[r] = fmaxf(rmax[r], __shfl_xor(rmax[r], dd));
    if (ln == 0) {
#pragma unroll
        for (int r = 0; r < 4; ++r) red[sh * 32 + rowb + r] = rmax[r];
    }
    __syncthreads();
    if (tid < 32)
        wsrow[(size_t)b * T_DIM + t0 + tid] = fmaxf(red[tid], red[32 + tid]);
}

// ============ fallback (round-1, verified): K/V staged per block, Vt row-major ============
__global__ __launch_bounds__(256, 2)
void attn_band_mfma(const float* __restrict__ Q, const float* __restrict__ K,
                    const unsigned short* __restrict__ Vt,
                    const float* __restrict__ Mask, const int* __restrict__ m_ptr,
                    float* __restrict__ wsrow)
{
    __shared__ __align__(16) char smem_raw[57600];
    short* SM = (short*)smem_raw;
    short* Kc = SM;
    short* Qc = SM + 288 * KROW;
    short* P  = SM;
    short* Vl = SM + 32 * PROW;
    float* pmax = (float*)(smem_raw + 56832);
    float* psum = pmax + 64;
    float* red  = psum + 64;

    const int h = blockIdx.x;
    const int logical = (h & 7) * 64 + (h >> 3);
    const int b  = logical >> 6;
    const int t0 = (logical & 63) * TB;

    const int tid = threadIdx.x;
    const int w = tid >> 6, lane = tid & 63, g = lane >> 4, ln = lane & 15;
    const int th = w >> 1, sh = w & 1;
    const int m  = m_ptr[0];

    const int s_lo = max(0, t0 - m);
    const int s_hi = min(T_DIM - 1, t0 + TB - 1 + m);

    const float* Qb = Q + (size_t)b * T_DIM * C_DIM;
    const float* Kb = K + (size_t)b * T_DIM * C_DIM;
    const unsigned short* Vtb = Vt + (size_t)b * C_DIM * T_DIM;

    f32x4 E[9];
    f32x4 zed = {0.f, 0.f, 0.f, 0.f};
#pragma unroll
    for (int i = 0; i < 9; ++i) E[i] = zed;

    for (int cc = 0; cc < C_DIM / 64; ++cc) {
        const int c0 = cc * 64;
        __syncthreads();
        for (int u = tid; u < 288 * 8; u += 256) {
            const int su = u >> 3, un = u & 7;
            const int s = min(s_lo + su, T_DIM - 1);
            const float4* src = (const float4*)(Kb + (size_t)s * C_DIM + c0 + un * 8);
            float4 x = src[0], y = src[1];
            uint4 o; o.x = pk2(x.x, x.y); o.y = pk2(x.z, x.w);
            o.z = pk2(y.x, y.y); o.w = pk2(y.z, y.w);
            *(uint4*)(Kc + su * KROW + un * 8) = o;
        }
        {
            const int su = tid >> 3, un = tid & 7;
            const float4* src = (const float4*)(Qb + (size_t)(t0 + su) * C_DIM + c0 + un * 8);
            float4 x = src[0], y = src[1];
            uint4 o; o.x = pk2(x.x, x.y); o.y = pk2(x.z, x.w);
            o.z = pk2(y.x, y.y); o.w = pk2(y.z, y.w);
            *(uint4*)(Qc + su * KROW + un * 8) = o;
        }
        __syncthreads();
        s16x8 aq[2];
#pragma unroll
        for (int kk = 0; kk < 2; ++kk)
            aq[kk] = *(const s16x8*)(Qc + (th * 16 + ln) * KROW + kk * 32 + g * 8);
#pragma unroll
        for (int i = 0; i < 9; ++i) {
            const int srow2 = (sh * 9 + i) * 16 + ln;
#pragma unroll
            for (int kk = 0; kk < 2; ++kk) {
                s16x8 bk = *(const s16x8*)(Kc + srow2 * KROW + kk * 32 + g * 8);
                E[i] = __builtin_amdgcn_mfma_f32_16x16x32_bf16(aq[kk], bk, E[i], 0, 0, 0);
            }
        }
    }

    const float scale = 0.03125f;
    const int rowb = th * 16 + g * 4;
    float lm[4];
#pragma unroll
    for (int r = 0; r < 4; ++r) lm[r] = -INFINITY;
    const int s_base = s_lo + sh * 144 + ln;
#pragma unroll
    for (int i = 0; i < 9; ++i) {
        const int s = s_base + i * 16;
#pragma unroll
        for (int r = 0; r < 4; ++r) {
            const int t = t0 + rowb + r;
            int d = t - s; d = d < 0 ? -d : d;
            const bool valid = (s <= s_hi) && (d <= m);
            float e = valid ? E[i][r] : -INFINITY;
            E[i][r] = e;
            lm[r] = fmaxf(lm[r], e);
        }
    }
#pragma unroll
    for (int r = 0; r < 4; ++r)
#pragma unroll
        for (int dd = 1; dd < 16; dd <<= 1) lm[r] = fmaxf(lm[r], __shfl_xor(lm[r], dd));
    if (ln == 0) {
#pragma unroll
        for (int r = 0; r < 4; ++r) pmax[sh * 32 + rowb + r] = lm[r];
    }
    __syncthreads();
    float Mr[4], sum[4];
#pragma unroll
    for (int r = 0; r < 4; ++r) {
        Mr[r] = fmaxf(pmax[rowb + r], pmax[32 + rowb + r]) * scale;
        sum[r] = 0.f;
    }
#pragma unroll
    for (int i = 0; i < 9; ++i)
#pragma unroll
        for (int r = 0; r < 4; ++r) {
            float e = __expf(E[i][r] * scale - Mr[r]);
            E[i][r] = e;
            sum[r] += e;
        }
#pragma unroll
    for (int r = 0; r < 4; ++r)
#pragma unroll
        for (int dd = 1; dd < 16; dd <<= 1) sum[r] += __shfl_xor(sum[r], dd);
    if (ln == 0) {
#pragma unroll
        for (int r = 0; r < 4; ++r) psum[sh * 32 + rowb + r] = sum[r];
    }
    __syncthreads();
    float inv[4];
#pragma unroll
    for (int r = 0; r < 4; ++r) inv[r] = 1.0f / (psum[rowb + r] + psum[32 + rowb + r]);
#pragma unroll
    for (int i = 0; i < 9; ++i) {
        const int col = sh * 144 + i * 16 + ln;
#pragma unroll
        for (int r = 0; r < 4; ++r)
            P[(rowb + r) * PROW + col] = (short)f2bf(E[i][r] * inv[r]);
    }
    __syncthreads();

    s16x8 pa[9];
#pragma unroll
    for (int kg = 0; kg < 9; ++kg)
        pa[kg] = *(const s16x8*)(P + (th * 16 + ln) * PROW + kg * 32 + g * 8);

    float maskv[4], rmax[4];
#pragma unroll
    for (int r = 0; r < 4; ++r) {
        maskv[r] = Mask[(size_t)b * T_DIM + t0 + rowb + r];
        rmax[r]  = -INFINITY;
    }

    for (int cc = 0; cc < C_DIM / 64; ++cc) {
        __syncthreads();
        for (int i2 = tid; i2 < 64 * 36; i2 += 256) {
            const int cr = i2 / 36, un = i2 - cr * 36;
            const int sb = min(s_lo + un * 8, T_DIM - 8);
            uint4 x = *(const uint4*)(Vtb + (size_t)(cc * 64 + cr) * T_DIM + sb);
            *(uint4*)(Vl + cr * PROW + un * 8) = x;
        }
        __syncthreads();
#pragma unroll
        for (int nbi = 0; nbi < 2; ++nbi) {
            const int crow = sh * 32 + nbi * 16 + ln;
            f32x4 O = zed;
#pragma unroll
            for (int kg = 0; kg < 9; ++kg) {
                s16x8 bv = *(const s16x8*)(Vl + crow * PROW + kg * 32 + g * 8);
                O = __builtin_amdgcn_mfma_f32_16x16x32_bf16(pa[kg], bv, O, 0, 0, 0);
            }
#pragma unroll
            for (int r = 0; r < 4; ++r)
                rmax[r] = fmaxf(rmax[r], O[r] * maskv[r]);
        }
    }
#pragma unroll
    for (int r = 0; r < 4; ++r)
#pragma unroll
        for (int dd = 1; dd < 16; dd <<= 1) rmax[r] = fmaxf(rmax[r], __shfl_xor(rmax[r], dd));
    if (ln == 0) {
#pragma unroll
        for (int r = 0; r < 4; ++r) red[sh * 32 + rowb + r] = rmax[r];
    }
    __syncthreads();
    if (tid < 32)
        wsrow[(size_t)b * T_DIM + t0 + tid] = fmaxf(red[tid], red[32 + tid]);
}

// out[b] = sum_t ws[b][t]
__global__ void reduce_b(const float* __restrict__ ws, float* __restrict__ out)
{
    const int b = blockIdx.x;
    float s = 0.f;
    for (int t = threadIdx.x; t < T_DIM; t += 256) s += ws[(size_t)b * T_DIM + t];
#pragma unroll
    for (int dd = 32; dd > 0; dd >>= 1) s += __shfl_xor(s, dd);
    __shared__ float acc[4];
    if ((threadIdx.x & 63) == 0) acc[threadIdx.x >> 6] = s;
    __syncthreads();
    if (threadIdx.x == 0) out[b] = acc[0] + acc[1] + acc[2] + acc[3];
}

extern "C" void kernel_launch(void* const* d_in, const int* in_sizes, int n_in,
                              void* d_out, int out_size, void* d_ws, size_t ws_size,
                              hipStream_t stream)
{
    const float* Q    = (const float*)d_in[0];
    const float* K    = (const float*)d_in[1];
    const float* V    = (const float*)d_in[2];
    const float* Mask = (const float*)d_in[3];
    const int*   m    = (const int*)d_in[4];
    float* out = (float*)d_out;

    const size_t frag_bytes = (size_t)B_DIM * T_DIM * C_DIM * 2;   // 33,554,432 per tensor
    const size_t need_main  = 3 * frag_bytes + (size_t)B_DIM * T_DIM * 4;

    if (ws_size >= need_main) {
        unsigned short* Qt  = (unsigned short*)d_ws;
        unsigned short* Kt  = (unsigned short*)((char*)d_ws + frag_bytes);
        unsigned short* Vtt = (unsigned short*)((char*)d_ws + 2 * frag_bytes);
        float* wsrow = (float*)((char*)d_ws + 3 * frag_bytes);
        tile_qk<<<dim3(256, B_DIM), 256, 0, stream>>>(Q, K, Qt, Kt);
        transpose_vx<<<dim3(T_DIM / 64, C_DIM / 64, B_DIM), 256, 0, stream>>>(V, Vtt, 1);
        attn_band_tiled<<<dim3((T_DIM / TB) * B_DIM), 256, 0, stream>>>(Qt, Kt, Vtt, Mask, m, wsrow);
        reduce_b<<<B_DIM, 256, 0, stream>>>(wsrow, out);
    } else {
        unsigned short* Vt = (unsigned short*)d_ws;
        float* wsrow = (float*)((char*)d_ws + frag_bytes);
        transpose_vx<<<dim3(T_DIM / 64, C_DIM / 64, B_DIM), 256, 0, stream>>>(V, Vt, 0);
        attn_band_mfma<<<dim3((T_DIM / TB) * B_DIM), 256, 0, stream>>>(Q, K, Vt, Mask, m, wsrow);
        reduce_b<<<B_DIM, 256, 0, stream>>>(wsrow, out);
    }
}

// Round 8
// 114.894 us; speedup vs baseline: 1.7059x; 1.1699x over previous
//
#include <hip/hip_runtime.h>
#include <math.h>

#define T_DIM 2048
#define C_DIM 1024
#define B_DIM 8
#define TB    32
#define KROW  72      // bf16 elems per Kc/Qc row (64 + 8 pad)  [fallback kernel]
#define PROW  296     // bf16 elems per P row (288 + 8 pad)

typedef float f32x4 __attribute__((ext_vector_type(4)));
typedef short s16x8 __attribute__((ext_vector_type(8)));

__device__ __forceinline__ unsigned short f2bf(float x) {
    union { float f; unsigned u; } v; v.f = x;
    unsigned r = v.u + 0x7fffu + ((v.u >> 16) & 1u);
    return (unsigned short)(r >> 16);
}
__device__ __forceinline__ unsigned pk2(float a, float b) {
    return (unsigned)f2bf(a) | ((unsigned)f2bf(b) << 16);
}

// async 16B/lane global->LDS DMA (no VGPR dest; wave-uniform LDS base + lane*16)
__device__ __forceinline__ void gll16(const unsigned short* g, short* l) {
    __builtin_amdgcn_global_load_lds(
        (const __attribute__((address_space(1))) unsigned int*)g,
        (__attribute__((address_space(3))) unsigned int*)l,
        16, 0, 0);
}

// ============ pre-pass A: Q,K f32 -> fragment-major bf16 Xt[b][tile][kk][lane][8] ============
__global__ __launch_bounds__(256)
void tile_qk(const float* __restrict__ Q, const float* __restrict__ K,
             unsigned short* __restrict__ Qt, unsigned short* __restrict__ Kt)
{
    const int bx   = blockIdx.x;            // 0..255
    const int tile = bx & 127;
    const float* src = (bx < 128) ? Q : K;
    unsigned short* dst = (bx < 128) ? Qt : Kt;
    const int b    = blockIdx.y;
    const int tid  = threadIdx.x;
    const int w = tid >> 6, l = tid & 63, g = l >> 4, ln = l & 15;
    const float* src_row = src + (size_t)(b * T_DIM + tile * 16 + ln) * C_DIM;
#pragma unroll
    for (int kki = 0; kki < 8; ++kki) {
        const int kk = kki * 4 + w;
        const float4* p = (const float4*)(src_row + kk * 32 + g * 8);
        float4 x = p[0], y = p[1];
        uint4 o;
        o.x = pk2(x.x, x.y); o.y = pk2(x.z, x.w);
        o.z = pk2(y.x, y.y); o.w = pk2(y.z, y.w);
        *(uint4*)(dst + (size_t)(((b * 128 + tile) * 32 + kk) * 64 + l) * 8) = o;
    }
}

// ============ pre-pass B: V f32 -> bf16, fragment-major Vtt OR row-major Vt ============
__global__ __launch_bounds__(256)
void transpose_vx(const float* __restrict__ V, unsigned short* __restrict__ out,
                  int frag_mode)
{
    __shared__ float buf[64 * 67];
    const int t0 = blockIdx.x * 64;
    const int c0 = blockIdx.y * 64;
    const int b  = blockIdx.z;
    const float* Vb = V + (size_t)b * T_DIM * C_DIM;

    for (int i = threadIdx.x; i < 64 * 64; i += 256) {
        const int r = i >> 6, c = i & 63;
        buf[r * 67 + c] = Vb[(size_t)(t0 + r) * C_DIM + c0 + c];
    }
    __syncthreads();
    const int t8 = threadIdx.x & 7;   // 8-t segment
    const int cl = threadIdx.x >> 3;  // 0..31
#pragma unroll
    for (int half = 0; half < 2; ++half) {
        const int c_loc = cl + half * 32;
        float v[8];
#pragma unroll
        for (int j = 0; j < 8; ++j) v[j] = buf[(t8 * 8 + j) * 67 + c_loc];
        uint4 o;
        o.x = pk2(v[0], v[1]); o.y = pk2(v[2], v[3]);
        o.z = pk2(v[4], v[5]); o.w = pk2(v[6], v[7]);
        if (frag_mode) {
            const int ct = (c0 + c_loc) >> 4, lnv = c_loc & 15;
            const int g = t8 & 3, sg = (t0 >> 5) + (t8 >> 2);
            *(uint4*)(out + (size_t)(((b * 64 + ct) * 64 + sg) * 64 + g * 16 + lnv) * 8) = o;
        } else {
            *(uint4*)(out + (size_t)(b * C_DIM + c0 + c_loc) * T_DIM + t0 + t8 * 8) = o;
        }
    }
}

// ============ banded attention: LDS-staged fragments via global_load_lds (m97 pattern) ============
// 256 thr = 4 waves (th = t-half of 32-row tile, sh = s-half / c-split).
__global__ __launch_bounds__(256, 2)
void attn_band_tiled(const unsigned short* __restrict__ Qt,
                     const unsigned short* __restrict__ Kt,
                     const unsigned short* __restrict__ Vtt,
                     const float* __restrict__ Mask, const int* __restrict__ m_ptr,
                     float* __restrict__ wsrow)
{
    // SMEM map (shorts):  phase1: Kbuf = [0, 20480)  (2 bufs x 20 frags x 512)
    //                     phase2/3: P = [0, 9472); Vbuf = [9728, 30208) (2 x 20 x 512)
    __shared__ __align__(16) short SMEM[30208];   // 60,416 B
    __shared__ float pmax[64], psum[64], red[64];
    short* Kbuf = SMEM;
    short* P    = SMEM;
    short* Vbuf = SMEM + 9728;

    // XCD-bijective swizzle: each XCD owns one batch's contiguous t-range
    const int h = blockIdx.x;
    const int logical = (h & 7) * 64 + (h >> 3);
    const int b  = logical >> 6;
    const int t0 = (logical & 63) * TB;

    const int tid = threadIdx.x;
    const int w = tid >> 6, lane = tid & 63, g = lane >> 4, ln = lane & 15;
    const int th = w >> 1, sh = w & 1;
    const int m  = m_ptr[0];

    const int s_lo = max(0, t0 - m);
    const int s_hi = min(T_DIM - 1, t0 + TB - 1 + m);
    const int sg0  = s_lo >> 5;               // 32-aligned by construction
    const int tq0  = t0 >> 4;

    const unsigned short* Qtb = Qt  + (size_t)b * 128 * 32 * 512;
    const unsigned short* Ktb = Kt  + (size_t)b * 128 * 32 * 512;
    const unsigned short* Vtb = Vtt + (size_t)b * 64 * 64 * 512;

    // ---- phase 1: E = Q.K^T; per kk stage 20 frags (18 K + 2 Q), dbuf, 1 barrier/iter ----
    f32x4 E[9];
    f32x4 zed = {0.f, 0.f, 0.f, 0.f};
#pragma unroll
    for (int i = 0; i < 9; ++i) E[i] = zed;

    // wave w stages frags f = 5w..5w+4; f<18: K tile min(sg0*2+f,127); f>=18: Q tile tq0+(f-18)
#define STAGE1(KN, NB)                                                              \
    {                                                                               \
        short* dstb = Kbuf + (NB) * 10240;                                          \
        _Pragma("unroll")                                                           \
        for (int f5 = 0; f5 < 5; ++f5) {                                            \
            const int f = w * 5 + f5;                                               \
            const unsigned short* gp;                                               \
            if (f < 18) gp = Ktb + ((size_t)(min(sg0 * 2 + f, 127) * 32 + (KN)) * 64 + lane) * 8; \
            else        gp = Qtb + ((size_t)((tq0 + (f - 18)) * 32 + (KN)) * 64 + lane) * 8;      \
            gll16(gp, dstb + f * 512);                                              \
        }                                                                           \
    }

    STAGE1(0, 0);
    __syncthreads();

#pragma unroll 2
    for (int kk = 0; kk < 32; ++kk) {
        const int cur = kk & 1;
        if (kk < 31) STAGE1(kk + 1, cur ^ 1);
        const short* cb = Kbuf + cur * 10240;
        s16x8 aq = *(const s16x8*)(cb + (18 + th) * 512 + lane * 8);
#pragma unroll
        for (int i = 0; i < 9; ++i) {
            s16x8 bk = *(const s16x8*)(cb + (sh * 9 + i) * 512 + lane * 8);
            E[i] = __builtin_amdgcn_mfma_f32_16x16x32_bf16(aq, bk, E[i], 0, 0, 0);
        }
        __syncthreads();
    }

    // ---- phase 2: exact softmax (cross-wave over the two s-halves) ----
    const float scale = 0.03125f;   // 1/sqrt(1024)
    const int rowb = th * 16 + g * 4;
    float lm[4];
#pragma unroll
    for (int r = 0; r < 4; ++r) lm[r] = -INFINITY;
    const int s_base = s_lo + sh * 144 + ln;
#pragma unroll
    for (int i = 0; i < 9; ++i) {
        const int s = s_base + i * 16;
#pragma unroll
        for (int r = 0; r < 4; ++r) {
            const int t = t0 + rowb + r;
            int d = t - s; d = d < 0 ? -d : d;
            const bool valid = (s <= s_hi) && (d <= m);
            float e = valid ? E[i][r] : -INFINITY;
            E[i][r] = e;
            lm[r] = fmaxf(lm[r], e);
        }
    }
#pragma unroll
    for (int r = 0; r < 4; ++r)
#pragma unroll
        for (int dd = 1; dd < 16; dd <<= 1) lm[r] = fmaxf(lm[r], __shfl_xor(lm[r], dd));
    if (ln == 0) {
#pragma unroll
        for (int r = 0; r < 4; ++r) pmax[sh * 32 + rowb + r] = lm[r];
    }
    __syncthreads();
    float Mr[4], sum[4];
#pragma unroll
    for (int r = 0; r < 4; ++r) {
        Mr[r] = fmaxf(pmax[rowb + r], pmax[32 + rowb + r]) * scale;
        sum[r] = 0.f;
    }
#pragma unroll
    for (int i = 0; i < 9; ++i)
#pragma unroll
        for (int r = 0; r < 4; ++r) {
            float e = __expf(E[i][r] * scale - Mr[r]);   // -inf -> 0 exactly
            E[i][r] = e;
            sum[r] += e;
        }
#pragma unroll
    for (int r = 0; r < 4; ++r)
#pragma unroll
        for (int dd = 1; dd < 16; dd <<= 1) sum[r] += __shfl_xor(sum[r], dd);
    if (ln == 0) {
#pragma unroll
        for (int r = 0; r < 4; ++r) psum[sh * 32 + rowb + r] = sum[r];
    }
    __syncthreads();
    float inv[4];
#pragma unroll
    for (int r = 0; r < 4; ++r) inv[r] = 1.0f / (psum[rowb + r] + psum[32 + rowb + r]);
#pragma unroll
    for (int i = 0; i < 9; ++i) {
        const int col = sh * 144 + i * 16 + ln;
#pragma unroll
        for (int r = 0; r < 4; ++r)
            P[(rowb + r) * PROW + col] = (short)f2bf(E[i][r] * inv[r]);
    }
    __syncthreads();

    // ---- phase 3: O = P @ V; per q two staged steps (kg 0-4, 5-8), dbuf, 1 barrier/step ----
    s16x8 pa[9];
#pragma unroll
    for (int kg = 0; kg < 9; ++kg)
        pa[kg] = *(const s16x8*)(P + (th * 16 + ln) * PROW + kg * 32 + g * 8);

    int sgc[9];
#pragma unroll
    for (int kg = 0; kg < 9; ++kg) sgc[kg] = min(sg0 + kg, 63);

    float maskv[4], rmax[4];
#pragma unroll
    for (int r = 0; r < 4; ++r) {
        maskv[r] = Mask[(size_t)b * T_DIM + t0 + rowb + r];
        rmax[r]  = -INFINITY;
    }

    // wave w stages ct = 4q+w, kg in [kgbase, kgbase+KG): slot (w*KG + e)
#define STAGE3(S, NB)                                                               \
    {                                                                               \
        const int q_ = (S) >> 1;                                                    \
        short* dstb = Vbuf + (NB) * 10240;                                          \
        const int ct_ = q_ * 4 + w;                                                 \
        if (((S) & 1) == 0) {                                                       \
            _Pragma("unroll")                                                       \
            for (int e = 0; e < 5; ++e)                                             \
                gll16(Vtb + ((size_t)(ct_ * 64 + sgc[e]) * 64 + lane) * 8,          \
                      dstb + (w * 5 + e) * 512);                                    \
        } else {                                                                    \
            _Pragma("unroll")                                                       \
            for (int e = 0; e < 4; ++e)                                             \
                gll16(Vtb + ((size_t)(ct_ * 64 + sgc[5 + e]) * 64 + lane) * 8,      \
                      dstb + (w * 4 + e) * 512);                                    \
        }                                                                           \
    }

    STAGE3(0, 0);
    __syncthreads();

    f32x4 O0 = zed, O1 = zed;
#pragma unroll 2
    for (int s = 0; s < 32; ++s) {
        const int cur = s & 1;
        if (s < 31) STAGE3(s + 1, cur ^ 1);
        const short* vb = Vbuf + cur * 10240;
        if ((s & 1) == 0) {
            O0 = zed; O1 = zed;
#pragma unroll
            for (int e = 0; e < 5; ++e) {
                s16x8 bv0 = *(const s16x8*)(vb + ((sh * 2    ) * 5 + e) * 512 + lane * 8);
                s16x8 bv1 = *(const s16x8*)(vb + ((sh * 2 + 1) * 5 + e) * 512 + lane * 8);
                O0 = __builtin_amdgcn_mfma_f32_16x16x32_bf16(pa[e], bv0, O0, 0, 0, 0);
                O1 = __builtin_amdgcn_mfma_f32_16x16x32_bf16(pa[e], bv1, O1, 0, 0, 0);
            }
        } else {
#pragma unroll
            for (int e = 0; e < 4; ++e) {
                s16x8 bv0 = *(const s16x8*)(vb + ((sh * 2    ) * 4 + e) * 512 + lane * 8);
                s16x8 bv1 = *(const s16x8*)(vb + ((sh * 2 + 1) * 4 + e) * 512 + lane * 8);
                O0 = __builtin_amdgcn_mfma_f32_16x16x32_bf16(pa[5 + e], bv0, O0, 0, 0, 0);
                O1 = __builtin_amdgcn_mfma_f32_16x16x32_bf16(pa[5 + e], bv1, O1, 0, 0, 0);
            }
#pragma unroll
            for (int r = 0; r < 4; ++r) {
                rmax[r] = fmaxf(rmax[r], O0[r] * maskv[r]);
                rmax[r] = fmaxf(rmax[r], O1[r] * maskv[r]);
            }
        }
        __syncthreads();
    }

#pragma unroll
    for (int r = 0; r < 4; ++r)
#pragma unroll
        for (int dd = 1; dd < 16; dd <<= 1) rmax[r] = fmaxf(rmax[r], __shfl_xor(rmax[r], dd));
    if (ln == 0) {
#pragma unroll
        for (int r = 0; r < 4; ++r) red[sh * 32 + rowb + r] = rmax[r];
    }
    __syncthreads();
    if (tid < 32)
        wsrow[(size_t)b * T_DIM + t0 + tid] = fmaxf(red[tid], red[32 + tid]);
}

// ============ fallback (round-1, verified): K/V staged per block, Vt row-major ============
__global__ __launch_bounds__(256, 2)
void attn_band_mfma(const float* __restrict__ Q, const float* __restrict__ K,
                    const unsigned short* __restrict__ Vt,
                    const float* __restrict__ Mask, const int* __restrict__ m_ptr,
                    float* __restrict__ wsrow)
{
    __shared__ __align__(16) char smem_raw[57600];
    short* SM = (short*)smem_raw;
    short* Kc = SM;
    short* Qc = SM + 288 * KROW;
    short* P  = SM;
    short* Vl = SM + 32 * PROW;
    float* pmax = (float*)(smem_raw + 56832);
    float* psum = pmax + 64;
    float* red  = psum + 64;

    const int h = blockIdx.x;
    const int logical = (h & 7) * 64 + (h >> 3);
    const int b  = logical >> 6;
    const int t0 = (logical & 63) * TB;

    const int tid = threadIdx.x;
    const int w = tid >> 6, lane = tid & 63, g = lane >> 4, ln = lane & 15;
    const int th = w >> 1, sh = w & 1;
    const int m  = m_ptr[0];

    const int s_lo = max(0, t0 - m);
    const int s_hi = min(T_DIM - 1, t0 + TB - 1 + m);

    const float* Qb = Q + (size_t)b * T_DIM * C_DIM;
    const float* Kb = K + (size_t)b * T_DIM * C_DIM;
    const unsigned short* Vtb = Vt + (size_t)b * C_DIM * T_DIM;

    f32x4 E[9];
    f32x4 zed = {0.f, 0.f, 0.f, 0.f};
#pragma unroll
    for (int i = 0; i < 9; ++i) E[i] = zed;

    for (int cc = 0; cc < C_DIM / 64; ++cc) {
        const int c0 = cc * 64;
        __syncthreads();
        for (int u = tid; u < 288 * 8; u += 256) {
            const int su = u >> 3, un = u & 7;
            const int s = min(s_lo + su, T_DIM - 1);
            const float4* src = (const float4*)(Kb + (size_t)s * C_DIM + c0 + un * 8);
            float4 x = src[0], y = src[1];
            uint4 o; o.x = pk2(x.x, x.y); o.y = pk2(x.z, x.w);
            o.z = pk2(y.x, y.y); o.w = pk2(y.z, y.w);
            *(uint4*)(Kc + su * KROW + un * 8) = o;
        }
        {
            const int su = tid >> 3, un = tid & 7;
            const float4* src = (const float4*)(Qb + (size_t)(t0 + su) * C_DIM + c0 + un * 8);
            float4 x = src[0], y = src[1];
            uint4 o; o.x = pk2(x.x, x.y); o.y = pk2(x.z, x.w);
            o.z = pk2(y.x, y.y); o.w = pk2(y.z, y.w);
            *(uint4*)(Qc + su * KROW + un * 8) = o;
        }
        __syncthreads();
        s16x8 aq[2];
#pragma unroll
        for (int kk = 0; kk < 2; ++kk)
            aq[kk] = *(const s16x8*)(Qc + (th * 16 + ln) * KROW + kk * 32 + g * 8);
#pragma unroll
        for (int i = 0; i < 9; ++i) {
            const int srow2 = (sh * 9 + i) * 16 + ln;
#pragma unroll
            for (int kk = 0; kk < 2; ++kk) {
                s16x8 bk = *(const s16x8*)(Kc + srow2 * KROW + kk * 32 + g * 8);
                E[i] = __builtin_amdgcn_mfma_f32_16x16x32_bf16(aq[kk], bk, E[i], 0, 0, 0);
            }
        }
    }

    const float scale = 0.03125f;
    const int rowb = th * 16 + g * 4;
    float lm[4];
#pragma unroll
    for (int r = 0; r < 4; ++r) lm[r] = -INFINITY;
    const int s_base = s_lo + sh * 144 + ln;
#pragma unroll
    for (int i = 0; i < 9; ++i) {
        const int s = s_base + i * 16;
#pragma unroll
        for (int r = 0; r < 4; ++r) {
            const int t = t0 + rowb + r;
            int d = t - s; d = d < 0 ? -d : d;
            const bool valid = (s <= s_hi) && (d <= m);
            float e = valid ? E[i][r] : -INFINITY;
            E[i][r] = e;
            lm[r] = fmaxf(lm[r], e);
        }
    }
#pragma unroll
    for (int r = 0; r < 4; ++r)
#pragma unroll
        for (int dd = 1; dd < 16; dd <<= 1) lm[r] = fmaxf(lm[r], __shfl_xor(lm[r], dd));
    if (ln == 0) {
#pragma unroll
        for (int r = 0; r < 4; ++r) pmax[sh * 32 + rowb + r] = lm[r];
    }
    __syncthreads();
    float Mr[4], sum[4];
#pragma unroll
    for (int r = 0; r < 4; ++r) {
        Mr[r] = fmaxf(pmax[rowb + r], pmax[32 + rowb + r]) * scale;
        sum[r] = 0.f;
    }
#pragma unroll
    for (int i = 0; i < 9; ++i)
#pragma unroll
        for (int r = 0; r < 4; ++r) {
            float e = __expf(E[i][r] * scale - Mr[r]);
            E[i][r] = e;
            sum[r] += e;
        }
#pragma unroll
    for (int r = 0; r < 4; ++r)
#pragma unroll
        for (int dd = 1; dd < 16; dd <<= 1) sum[r] += __shfl_xor(sum[r], dd);
    if (ln == 0) {
#pragma unroll
        for (int r = 0; r < 4; ++r) psum[sh * 32 + rowb + r] = sum[r];
    }
    __syncthreads();
    float inv[4];
#pragma unroll
    for (int r = 0; r < 4; ++r) inv[r] = 1.0f / (psum[rowb + r] + psum[32 + rowb + r]);
#pragma unroll
    for (int i = 0; i < 9; ++i) {
        const int col = sh * 144 + i * 16 + ln;
#pragma unroll
        for (int r = 0; r < 4; ++r)
            P[(rowb + r) * PROW + col] = (short)f2bf(E[i][r] * inv[r]);
    }
    __syncthreads();

    s16x8 pa[9];
#pragma unroll
    for (int kg = 0; kg < 9; ++kg)
        pa[kg] = *(const s16x8*)(P + (th * 16 + ln) * PROW + kg * 32 + g * 8);

    float maskv[4], rmax[4];
#pragma unroll
    for (int r = 0; r < 4; ++r) {
        maskv[r] = Mask[(size_t)b * T_DIM + t0 + rowb + r];
        rmax[r]  = -INFINITY;
    }

    for (int cc = 0; cc < C_DIM / 64; ++cc) {
        __syncthreads();
        for (int i2 = tid; i2 < 64 * 36; i2 += 256) {
            const int cr = i2 / 36, un = i2 - cr * 36;
            const int sb = min(s_lo + un * 8, T_DIM - 8);
            uint4 x = *(const uint4*)(Vtb + (size_t)(cc * 64 + cr) * T_DIM + sb);
            *(uint4*)(Vl + cr * PROW + un * 8) = x;
        }
        __syncthreads();
#pragma unroll
        for (int nbi = 0; nbi < 2; ++nbi) {
            const int crow = sh * 32 + nbi * 16 + ln;
            f32x4 O = zed;
#pragma unroll
            for (int kg = 0; kg < 9; ++kg) {
                s16x8 bv = *(const s16x8*)(Vl + crow * PROW + kg * 32 + g * 8);
                O = __builtin_amdgcn_mfma_f32_16x16x32_bf16(pa[kg], bv, O, 0, 0, 0);
            }
#pragma unroll
            for (int r = 0; r < 4; ++r)
                rmax[r] = fmaxf(rmax[r], O[r] * maskv[r]);
        }
    }
#pragma unroll
    for (int r = 0; r < 4; ++r)
#pragma unroll
        for (int dd = 1; dd < 16; dd <<= 1) rmax[r] = fmaxf(rmax[r], __shfl_xor(rmax[r], dd));
    if (ln == 0) {
#pragma unroll
        for (int r = 0; r < 4; ++r) red[sh * 32 + rowb + r] = rmax[r];
    }
    __syncthreads();
    if (tid < 32)
        wsrow[(size_t)b * T_DIM + t0 + tid] = fmaxf(red[tid], red[32 + tid]);
}

// out[b] = sum_t ws[b][t]
__global__ void reduce_b(const float* __restrict__ ws, float* __restrict__ out)
{
    const int b = blockIdx.x;
    float s = 0.f;
    for (int t = threadIdx.x; t < T_DIM; t += 256) s += ws[(size_t)b * T_DIM + t];
#pragma unroll
    for (int dd = 32; dd > 0; dd >>= 1) s += __shfl_xor(s, dd);
    __shared__ float acc[4];
    if ((threadIdx.x & 63) == 0) acc[threadIdx.x >> 6] = s;
    __syncthreads();
    if (threadIdx.x == 0) out[b] = acc[0] + acc[1] + acc[2] + acc[3];
}

extern "C" void kernel_launch(void* const* d_in, const int* in_sizes, int n_in,
                              void* d_out, int out_size, void* d_ws, size_t ws_size,
                              hipStream_t stream)
{
    const float* Q    = (const float*)d_in[0];
    const float* K    = (const float*)d_in[1];
    const float* V    = (const float*)d_in[2];
    const float* Mask = (const float*)d_in[3];
    const int*   m    = (const int*)d_in[4];
    float* out = (float*)d_out;

    const size_t frag_bytes = (size_t)B_DIM * T_DIM * C_DIM * 2;   // 33,554,432 per tensor
    const size_t need_main  = 3 * frag_bytes + (size_t)B_DIM * T_DIM * 4;

    if (ws_size >= need_main) {
        unsigned short* Qt  = (unsigned short*)d_ws;
        unsigned short* Kt  = (unsigned short*)((char*)d_ws + frag_bytes);
        unsigned short* Vtt = (unsigned short*)((char*)d_ws + 2 * frag_bytes);
        float* wsrow = (float*)((char*)d_ws + 3 * frag_bytes);
        tile_qk<<<dim3(256, B_DIM), 256, 0, stream>>>(Q, K, Qt, Kt);
        transpose_vx<<<dim3(T_DIM / 64, C_DIM / 64, B_DIM), 256, 0, stream>>>(V, Vtt, 1);
        attn_band_tiled<<<dim3((T_DIM / TB) * B_DIM), 256, 0, stream>>>(Qt, Kt, Vtt, Mask, m, wsrow);
        reduce_b<<<B_DIM, 256, 0, stream>>>(wsrow, out);
    } else {
        unsigned short* Vt = (unsigned short*)d_ws;
        float* wsrow = (float*)((char*)d_ws + frag_bytes);
        transpose_vx<<<dim3(T_DIM / 64, C_DIM / 64, B_DIM), 256, 0, stream>>>(V, Vt, 0);
        attn_band_mfma<<<dim3((T_DIM / TB) * B_DIM), 256, 0, stream>>>(Q, K, Vt, Mask, m, wsrow);
        reduce_b<<<B_DIM, 256, 0, stream>>>(wsrow, out);
    }
}

// Round 10
// 110.623 us; speedup vs baseline: 1.7718x; 1.0386x over previous
//
#include <hip/hip_runtime.h>
#include <math.h>

#define T_DIM 2048
#define C_DIM 1024
#define B_DIM 8
#define TB    32
#define KROW  72      // bf16 elems per Kc/Qc row (64 + 8 pad)  [fallback kernel]
#define PROW  296     // bf16 elems per P row (288 + 8 pad)

typedef float f32x4 __attribute__((ext_vector_type(4)));
typedef short s16x8 __attribute__((ext_vector_type(8)));

__device__ __forceinline__ unsigned short f2bf(float x) {
    union { float f; unsigned u; } v; v.f = x;
    unsigned r = v.u + 0x7fffu + ((v.u >> 16) & 1u);
    return (unsigned short)(r >> 16);
}
__device__ __forceinline__ unsigned pk2(float a, float b) {
    return (unsigned)f2bf(a) | ((unsigned)f2bf(b) << 16);
}

// async 16B/lane global->LDS DMA (no VGPR dest; wave-uniform LDS base + lane*16)
__device__ __forceinline__ void gll16(const unsigned short* g, short* l) {
    __builtin_amdgcn_global_load_lds(
        (const __attribute__((address_space(1))) unsigned int*)g,
        (__attribute__((address_space(3))) unsigned int*)l,
        16, 0, 0);
}

// ============ fused pre-pass: Q,K,V f32 -> fragment-major bf16 ============
// Qt/Kt[b][tile][kk][lane][8]: elem = X[b][tile*16+(l&15)][kk*32+(l>>4)*8+j]
// Vtt [b][ct][sg][lane][8]:    elem = V[b][sg*32+(l>>4)*8+j][ct*16+(l&15)]
// grid.x = 640: bx<64 -> Q slab bx; bx<128 -> K slab bx-64; else V tile vi = bx-128.
// Q/K branch: 32-row slab, coalesced 1KB/instr reads -> LDS (odd-pad) -> frag emit.
__global__ __launch_bounds__(256)
void prep_qkv(const float* __restrict__ Q, const float* __restrict__ K,
              const float* __restrict__ V, unsigned short* __restrict__ Qt,
              unsigned short* __restrict__ Kt, unsigned short* __restrict__ Vtt)
{
    __shared__ __align__(16) char RAW[33920];   // union: QK [32][265] f32 / V [64][67] f32
    const int bx = blockIdx.x, b = blockIdx.y, tid = threadIdx.x;

    if (bx < 128) {
        // ---- Q/K slab: 32 rows x 1024 cols, 4 col-chunks of 256 ----
        float* buf = (float*)RAW;               // [32][265]
        const int slab = bx & 63;               // 0..63  (64 slabs of 32 rows)
        const float* src = (bx < 64) ? Q : K;
        unsigned short* dst = (bx < 64) ? Qt : Kt;
        const float* srow = src + (size_t)(b * T_DIM + slab * 32) * C_DIM;
#pragma unroll
        for (int cc = 0; cc < 4; ++cc) {
            __syncthreads();
            // stage-in: wave reads 1KB contiguous per instr
            for (int u = tid; u < 32 * 64; u += 256) {
                const int r = u >> 6, c4 = u & 63;
                *(float4*)(buf + r * 265 + c4 * 4) =
                    *(const float4*)(srow + (size_t)r * C_DIM + cc * 256 + c4 * 4);
            }
            __syncthreads();
            // emit: 16 frags (2 sub-tiles x 8 kk); scalar LDS reads (odd pad);
            // global writes 1KB contiguous per wave-instr
            for (int u = tid; u < 16 * 64; u += 256) {
                const int f = u >> 6, l = u & 63;
                const int sub = f >> 3, kk_loc = f & 7;
                const int ln = l & 15, g = l >> 4;
                const float* p = buf + (sub * 16 + ln) * 265 + kk_loc * 32 + g * 8;
                uint4 o;
                o.x = pk2(p[0], p[1]); o.y = pk2(p[2], p[3]);
                o.z = pk2(p[4], p[5]); o.w = pk2(p[6], p[7]);
                const int tile = slab * 2 + sub;        // 0..127
                const int kk = cc * 8 + kk_loc;         // 0..31
                *(uint4*)(dst + (size_t)(((b * 128 + tile) * 32 + kk) * 64 + l) * 8) = o;
            }
        }
    } else {
        // ---- V tile: 64 t x 64 c, transpose + frag emit (transpose_vx verbatim) ----
        float* buf = (float*)RAW;               // [64][67]
        const int vi = bx - 128;                // 0..511
        const int t0 = (vi & 31) * 64;
        const int c0 = (vi >> 5) * 64;
        const float* Vb = V + (size_t)b * T_DIM * C_DIM;

        for (int i = tid; i < 64 * 64; i += 256) {
            const int r = i >> 6, c = i & 63;
            buf[r * 67 + c] = Vb[(size_t)(t0 + r) * C_DIM + c0 + c];
        }
        __syncthreads();
        const int t8 = tid & 7;   // 8-t segment
        const int cl = tid >> 3;  // 0..31
#pragma unroll
        for (int half = 0; half < 2; ++half) {
            const int c_loc = cl + half * 32;
            float v[8];
#pragma unroll
            for (int j = 0; j < 8; ++j) v[j] = buf[(t8 * 8 + j) * 67 + c_loc];
            uint4 o;
            o.x = pk2(v[0], v[1]); o.y = pk2(v[2], v[3]);
            o.z = pk2(v[4], v[5]); o.w = pk2(v[6], v[7]);
            const int ct = (c0 + c_loc) >> 4, lnv = c_loc & 15;
            const int g = t8 & 3, sg = (t0 >> 5) + (t8 >> 2);
            *(uint4*)(Vtt + (size_t)(((b * 64 + ct) * 64 + sg) * 64 + g * 16 + lnv) * 8) = o;
        }
    }
}

// ============ pre-pass (fallback only): V f32 -> bf16 row-major Vt[b][c][t] ============
__global__ __launch_bounds__(256)
void transpose_vx(const float* __restrict__ V, unsigned short* __restrict__ out,
                  int frag_mode)
{
    __shared__ float buf[64 * 67];
    const int t0 = blockIdx.x * 64;
    const int c0 = blockIdx.y * 64;
    const int b  = blockIdx.z;
    const float* Vb = V + (size_t)b * T_DIM * C_DIM;

    for (int i = threadIdx.x; i < 64 * 64; i += 256) {
        const int r = i >> 6, c = i & 63;
        buf[r * 67 + c] = Vb[(size_t)(t0 + r) * C_DIM + c0 + c];
    }
    __syncthreads();
    const int t8 = threadIdx.x & 7;   // 8-t segment
    const int cl = threadIdx.x >> 3;  // 0..31
#pragma unroll
    for (int half = 0; half < 2; ++half) {
        const int c_loc = cl + half * 32;
        float v[8];
#pragma unroll
        for (int j = 0; j < 8; ++j) v[j] = buf[(t8 * 8 + j) * 67 + c_loc];
        uint4 o;
        o.x = pk2(v[0], v[1]); o.y = pk2(v[2], v[3]);
        o.z = pk2(v[4], v[5]); o.w = pk2(v[6], v[7]);
        if (frag_mode) {
            const int ct = (c0 + c_loc) >> 4, lnv = c_loc & 15;
            const int g = t8 & 3, sg = (t0 >> 5) + (t8 >> 2);
            *(uint4*)(out + (size_t)(((b * 64 + ct) * 64 + sg) * 64 + g * 16 + lnv) * 8) = o;
        } else {
            *(uint4*)(out + (size_t)(b * C_DIM + c0 + c_loc) * T_DIM + t0 + t8 * 8) = o;
        }
    }
}

// ============ banded attention: LDS-staged fragments via global_load_lds (verified r8) ============
// 256 thr = 4 waves (th = t-half of 32-row tile, sh = s-half / c-split).
__global__ __launch_bounds__(256, 2)
void attn_band_tiled(const unsigned short* __restrict__ Qt,
                     const unsigned short* __restrict__ Kt,
                     const unsigned short* __restrict__ Vtt,
                     const float* __restrict__ Mask, const int* __restrict__ m_ptr,
                     float* __restrict__ wsrow)
{
    // SMEM map (shorts):  phase1: Kbuf = [0, 20480)  (2 bufs x 20 frags x 512)
    //                     phase2/3: P = [0, 9472); Vbuf = [9728, 30208) (2 x 20 x 512)
    __shared__ __align__(16) short SMEM[30208];   // 60,416 B
    __shared__ float pmax[64], psum[64], red[64];
    short* Kbuf = SMEM;
    short* P    = SMEM;
    short* Vbuf = SMEM + 9728;

    // XCD-bijective swizzle: each XCD owns one batch's contiguous t-range
    const int h = blockIdx.x;
    const int logical = (h & 7) * 64 + (h >> 3);
    const int b  = logical >> 6;
    const int t0 = (logical & 63) * TB;

    const int tid = threadIdx.x;
    const int w = tid >> 6, lane = tid & 63, g = lane >> 4, ln = lane & 15;
    const int th = w >> 1, sh = w & 1;
    const int m  = m_ptr[0];

    const int s_lo = max(0, t0 - m);
    const int s_hi = min(T_DIM - 1, t0 + TB - 1 + m);
    const int sg0  = s_lo >> 5;               // 32-aligned by construction
    const int tq0  = t0 >> 4;

    const unsigned short* Qtb = Qt  + (size_t)b * 128 * 32 * 512;
    const unsigned short* Ktb = Kt  + (size_t)b * 128 * 32 * 512;
    const unsigned short* Vtb = Vtt + (size_t)b * 64 * 64 * 512;

    // ---- phase 1: E = Q.K^T; per kk stage 20 frags (18 K + 2 Q), dbuf, 1 barrier/iter ----
    f32x4 E[9];
    f32x4 zed = {0.f, 0.f, 0.f, 0.f};
#pragma unroll
    for (int i = 0; i < 9; ++i) E[i] = zed;

    // wave w stages frags f = 5w..5w+4; f<18: K tile min(sg0*2+f,127); f>=18: Q tile tq0+(f-18)
#define STAGE1(KN, NB)                                                              \
    {                                                                               \
        short* dstb = Kbuf + (NB) * 10240;                                          \
        _Pragma("unroll")                                                           \
        for (int f5 = 0; f5 < 5; ++f5) {                                            \
            const int f = w * 5 + f5;                                               \
            const unsigned short* gp;                                               \
            if (f < 18) gp = Ktb + ((size_t)(min(sg0 * 2 + f, 127) * 32 + (KN)) * 64 + lane) * 8; \
            else        gp = Qtb + ((size_t)((tq0 + (f - 18)) * 32 + (KN)) * 64 + lane) * 8;      \
            gll16(gp, dstb + f * 512);                                              \
        }                                                                           \
    }

    STAGE1(0, 0);
    __syncthreads();

#pragma unroll 2
    for (int kk = 0; kk < 32; ++kk) {
        const int cur = kk & 1;
        if (kk < 31) STAGE1(kk + 1, cur ^ 1);
        const short* cb = Kbuf + cur * 10240;
        s16x8 aq = *(const s16x8*)(cb + (18 + th) * 512 + lane * 8);
#pragma unroll
        for (int i = 0; i < 9; ++i) {
            s16x8 bk = *(const s16x8*)(cb + (sh * 9 + i) * 512 + lane * 8);
            E[i] = __builtin_amdgcn_mfma_f32_16x16x32_bf16(aq, bk, E[i], 0, 0, 0);
        }
        __syncthreads();
    }

    // ---- phase 2: exact softmax (cross-wave over the two s-halves) ----
    const float scale = 0.03125f;   // 1/sqrt(1024)
    const int rowb = th * 16 + g * 4;
    float lm[4];
#pragma unroll
    for (int r = 0; r < 4; ++r) lm[r] = -INFINITY;
    const int s_base = s_lo + sh * 144 + ln;
#pragma unroll
    for (int i = 0; i < 9; ++i) {
        const int s = s_base + i * 16;
#pragma unroll
        for (int r = 0; r < 4; ++r) {
            const int t = t0 + rowb + r;
            int d = t - s; d = d < 0 ? -d : d;
            const bool valid = (s <= s_hi) && (d <= m);
            float e = valid ? E[i][r] : -INFINITY;
            E[i][r] = e;
            lm[r] = fmaxf(lm[r], e);
        }
    }
#pragma unroll
    for (int r = 0; r < 4; ++r)
#pragma unroll
        for (int dd = 1; dd < 16; dd <<= 1) lm[r] = fmaxf(lm[r], __shfl_xor(lm[r], dd));
    if (ln == 0) {
#pragma unroll
        for (int r = 0; r < 4; ++r) pmax[sh * 32 + rowb + r] = lm[r];
    }
    __syncthreads();
    float Mr[4], sum[4];
#pragma unroll
    for (int r = 0; r < 4; ++r) {
        Mr[r] = fmaxf(pmax[rowb + r], pmax[32 + rowb + r]) * scale;
        sum[r] = 0.f;
    }
#pragma unroll
    for (int i = 0; i < 9; ++i)
#pragma unroll
        for (int r = 0; r < 4; ++r) {
            float e = __expf(E[i][r] * scale - Mr[r]);   // -inf -> 0 exactly
            E[i][r] = e;
            sum[r] += e;
        }
#pragma unroll
    for (int r = 0; r < 4; ++r)
#pragma unroll
        for (int dd = 1; dd < 16; dd <<= 1) sum[r] += __shfl_xor(sum[r], dd);
    if (ln == 0) {
#pragma unroll
        for (int r = 0; r < 4; ++r) psum[sh * 32 + rowb + r] = sum[r];
    }
    __syncthreads();
    float inv[4];
#pragma unroll
    for (int r = 0; r < 4; ++r) inv[r] = 1.0f / (psum[rowb + r] + psum[32 + rowb + r]);
#pragma unroll
    for (int i = 0; i < 9; ++i) {
        const int col = sh * 144 + i * 16 + ln;
#pragma unroll
        for (int r = 0; r < 4; ++r)
            P[(rowb + r) * PROW + col] = (short)f2bf(E[i][r] * inv[r]);
    }
    __syncthreads();

    // ---- phase 3: O = P @ V; per q two staged steps (kg 0-4, 5-8), dbuf, 1 barrier/step ----
    s16x8 pa[9];
#pragma unroll
    for (int kg = 0; kg < 9; ++kg)
        pa[kg] = *(const s16x8*)(P + (th * 16 + ln) * PROW + kg * 32 + g * 8);

    int sgc[9];
#pragma unroll
    for (int kg = 0; kg < 9; ++kg) sgc[kg] = min(sg0 + kg, 63);

    float maskv[4], rmax[4];
#pragma unroll
    for (int r = 0; r < 4; ++r) {
        maskv[r] = Mask[(size_t)b * T_DIM + t0 + rowb + r];
        rmax[r]  = -INFINITY;
    }

    // wave w stages ct = 4q+w, kg in [kgbase, kgbase+KG): slot (w*KG + e)
#define STAGE3(S, NB)                                                               \
    {                                                                               \
        const int q_ = (S) >> 1;                                                    \
        short* dstb = Vbuf + (NB) * 10240;                                          \
        const int ct_ = q_ * 4 + w;                                                 \
        if (((S) & 1) == 0) {                                                       \
            _Pragma("unroll")                                                       \
            for (int e = 0; e < 5; ++e)                                             \
                gll16(Vtb + ((size_t)(ct_ * 64 + sgc[e]) * 64 + lane) * 8,          \
                      dstb + (w * 5 + e) * 512);                                    \
        } else {                                                                    \
            _Pragma("unroll")                                                       \
            for (int e = 0; e < 4; ++e)                                             \
                gll16(Vtb + ((size_t)(ct_ * 64 + sgc[5 + e]) * 64 + lane) * 8,      \
                      dstb + (w * 4 + e) * 512);                                    \
        }                                                                           \
    }

    STAGE3(0, 0);
    __syncthreads();

    f32x4 O0 = zed, O1 = zed;
#pragma unroll 2
    for (int s = 0; s < 32; ++s) {
        const int cur = s & 1;
        if (s < 31) STAGE3(s + 1, cur ^ 1);
        const short* vb = Vbuf + cur * 10240;
        if ((s & 1) == 0) {
            O0 = zed; O1 = zed;
#pragma unroll
            for (int e = 0; e < 5; ++e) {
                s16x8 bv0 = *(const s16x8*)(vb + ((sh * 2    ) * 5 + e) * 512 + lane * 8);
                s16x8 bv1 = *(const s16x8*)(vb + ((sh * 2 + 1) * 5 + e) * 512 + lane * 8);
                O0 = __builtin_amdgcn_mfma_f32_16x16x32_bf16(pa[e], bv0, O0, 0, 0, 0);
                O1 = __builtin_amdgcn_mfma_f32_16x16x32_bf16(pa[e], bv1, O1, 0, 0, 0);
            }
        } else {
#pragma unroll
            for (int e = 0; e < 4; ++e) {
                s16x8 bv0 = *(const s16x8*)(vb + ((sh * 2    ) * 4 + e) * 512 + lane * 8);
                s16x8 bv1 = *(const s16x8*)(vb + ((sh * 2 + 1) * 4 + e) * 512 + lane * 8);
                O0 = __builtin_amdgcn_mfma_f32_16x16x32_bf16(pa[5 + e], bv0, O0, 0, 0, 0);
                O1 = __builtin_amdgcn_mfma_f32_16x16x32_bf16(pa[5 + e], bv1, O1, 0, 0, 0);
            }
#pragma unroll
            for (int r = 0; r < 4; ++r) {
                rmax[r] = fmaxf(rmax[r], O0[r] * maskv[r]);
                rmax[r] = fmaxf(rmax[r], O1[r] * maskv[r]);
            }
        }
        __syncthreads();
    }

#pragma unroll
    for (int r = 0; r < 4; ++r)
#pragma unroll
        for (int dd = 1; dd < 16; dd <<= 1) rmax[r] = fmaxf(rmax[r], __shfl_xor(rmax[r], dd));
    if (ln == 0) {
#pragma unroll
        for (int r = 0; r < 4; ++r) red[sh * 32 + rowb + r] = rmax[r];
    }
    __syncthreads();
    if (tid < 32)
        wsrow[(size_t)b * T_DIM + t0 + tid] = fmaxf(red[tid], red[32 + tid]);
}

// ============ fallback (round-1, verified): K/V staged per block, Vt row-major ============
__global__ __launch_bounds__(256, 2)
void attn_band_mfma(const float* __restrict__ Q, const float* __restrict__ K,
                    const unsigned short* __restrict__ Vt,
                    const float* __restrict__ Mask, const int* __restrict__ m_ptr,
                    float* __restrict__ wsrow)
{
    __shared__ __align__(16) char smem_raw[57600];
    short* SM = (short*)smem_raw;
    short* Kc = SM;
    short* Qc = SM + 288 * KROW;
    short* P  = SM;
    short* Vl = SM + 32 * PROW;
    float* pmax = (float*)(smem_raw + 56832);
    float* psum = pmax + 64;
    float* red  = psum + 64;

    const int h = blockIdx.x;
    const int logical = (h & 7) * 64 + (h >> 3);
    const int b  = logical >> 6;
    const int t0 = (logical & 63) * TB;

    const int tid = threadIdx.x;
    const int w = tid >> 6, lane = tid & 63, g = lane >> 4, ln = lane & 15;
    const int th = w >> 1, sh = w & 1;
    const int m  = m_ptr[0];

    const int s_lo = max(0, t0 - m);
    const int s_hi = min(T_DIM - 1, t0 + TB - 1 + m);

    const float* Qb = Q + (size_t)b * T_DIM * C_DIM;
    const float* Kb = K + (size_t)b * T_DIM * C_DIM;
    const unsigned short* Vtb = Vt + (size_t)b * C_DIM * T_DIM;

    f32x4 E[9];
    f32x4 zed = {0.f, 0.f, 0.f, 0.f};
#pragma unroll
    for (int i = 0; i < 9; ++i) E[i] = zed;

    for (int cc = 0; cc < C_DIM / 64; ++cc) {
        const int c0 = cc * 64;
        __syncthreads();
        for (int u = tid; u < 288 * 8; u += 256) {
            const int su = u >> 3, un = u & 7;
            const int s = min(s_lo + su, T_DIM - 1);
            const float4* src = (const float4*)(Kb + (size_t)s * C_DIM + c0 + un * 8);
            float4 x = src[0], y = src[1];
            uint4 o; o.x = pk2(x.x, x.y); o.y = pk2(x.z, x.w);
            o.z = pk2(y.x, y.y); o.w = pk2(y.z, y.w);
            *(uint4*)(Kc + su * KROW + un * 8) = o;
        }
        {
            const int su = tid >> 3, un = tid & 7;
            const float4* src = (const float4*)(Qb + (size_t)(t0 + su) * C_DIM + c0 + un * 8);
            float4 x = src[0], y = src[1];
            uint4 o; o.x = pk2(x.x, x.y); o.y = pk2(x.z, x.w);
            o.z = pk2(y.x, y.y); o.w = pk2(y.z, y.w);
            *(uint4*)(Qc + su * KROW + un * 8) = o;
        }
        __syncthreads();
        s16x8 aq[2];
#pragma unroll
        for (int kk = 0; kk < 2; ++kk)
            aq[kk] = *(const s16x8*)(Qc + (th * 16 + ln) * KROW + kk * 32 + g * 8);
#pragma unroll
        for (int i = 0; i < 9; ++i) {
            const int srow2 = (sh * 9 + i) * 16 + ln;
#pragma unroll
            for (int kk = 0; kk < 2; ++kk) {
                s16x8 bk = *(const s16x8*)(Kc + srow2 * KROW + kk * 32 + g * 8);
                E[i] = __builtin_amdgcn_mfma_f32_16x16x32_bf16(aq[kk], bk, E[i], 0, 0, 0);
            }
        }
    }

    const float scale = 0.03125f;
    const int rowb = th * 16 + g * 4;
    float lm[4];
#pragma unroll
    for (int r = 0; r < 4; ++r) lm[r] = -INFINITY;
    const int s_base = s_lo + sh * 144 + ln;
#pragma unroll
    for (int i = 0; i < 9; ++i) {
        const int s = s_base + i * 16;
#pragma unroll
        for (int r = 0; r < 4; ++r) {
            const int t = t0 + rowb + r;
            int d = t - s; d = d < 0 ? -d : d;
            const bool valid = (s <= s_hi) && (d <= m);
            float e = valid ? E[i][r] : -INFINITY;
            E[i][r] = e;
            lm[r] = fmaxf(lm[r], e);
        }
    }
#pragma unroll
    for (int r = 0; r < 4; ++r)
#pragma unroll
        for (int dd = 1; dd < 16; dd <<= 1) lm[r] = fmaxf(lm[r], __shfl_xor(lm[r], dd));
    if (ln == 0) {
#pragma unroll
        for (int r = 0; r < 4; ++r) pmax[sh * 32 + rowb + r] = lm[r];
    }
    __syncthreads();
    float Mr[4], sum[4];
#pragma unroll
    for (int r = 0; r < 4; ++r) {
        Mr[r] = fmaxf(pmax[rowb + r], pmax[32 + rowb + r]) * scale;
        sum[r] = 0.f;
    }
#pragma unroll
    for (int i = 0; i < 9; ++i)
#pragma unroll
        for (int r = 0; r < 4; ++r) {
            float e = __expf(E[i][r] * scale - Mr[r]);
            E[i][r] = e;
            sum[r] += e;
        }
#pragma unroll
    for (int r = 0; r < 4; ++r)
#pragma unroll
        for (int dd = 1; dd < 16; dd <<= 1) sum[r] += __shfl_xor(sum[r], dd);
    if (ln == 0) {
#pragma unroll
        for (int r = 0; r < 4; ++r) psum[sh * 32 + rowb + r] = sum[r];
    }
    __syncthreads();
    float inv[4];
#pragma unroll
    for (int r = 0; r < 4; ++r) inv[r] = 1.0f / (psum[rowb + r] + psum[32 + rowb + r]);
#pragma unroll
    for (int i = 0; i < 9; ++i) {
        const int col = sh * 144 + i * 16 + ln;
#pragma unroll
        for (int r = 0; r < 4; ++r)
            P[(rowb + r) * PROW + col] = (short)f2bf(E[i][r] * inv[r]);
    }
    __syncthreads();

    s16x8 pa[9];
#pragma unroll
    for (int kg = 0; kg < 9; ++kg)
        pa[kg] = *(const s16x8*)(P + (th * 16 + ln) * PROW + kg * 32 + g * 8);

    float maskv[4], rmax[4];
#pragma unroll
    for (int r = 0; r < 4; ++r) {
        maskv[r] = Mask[(size_t)b * T_DIM + t0 + rowb + r];
        rmax[r]  = -INFINITY;
    }

    for (int cc = 0; cc < C_DIM / 64; ++cc) {
        __syncthreads();
        for (int i2 = tid; i2 < 64 * 36; i2 += 256) {
            const int cr = i2 / 36, un = i2 - cr * 36;
            const int sb = min(s_lo + un * 8, T_DIM - 8);
            uint4 x = *(const uint4*)(Vtb + (size_t)(cc * 64 + cr) * T_DIM + sb);
            *(uint4*)(Vl + cr * PROW + un * 8) = x;
        }
        __syncthreads();
#pragma unroll
        for (int nbi = 0; nbi < 2; ++nbi) {
            const int crow = sh * 32 + nbi * 16 + ln;
            f32x4 O = zed;
#pragma unroll
            for (int kg = 0; kg < 9; ++kg) {
                s16x8 bv = *(const s16x8*)(Vl + crow * PROW + kg * 32 + g * 8);
                O = __builtin_amdgcn_mfma_f32_16x16x32_bf16(pa[kg], bv, O, 0, 0, 0);
            }
#pragma unroll
            for (int r = 0; r < 4; ++r)
                rmax[r] = fmaxf(rmax[r], O[r] * maskv[r]);
        }
    }
#pragma unroll
    for (int r = 0; r < 4; ++r)
#pragma unroll
        for (int dd = 1; dd < 16; dd <<= 1) rmax[r] = fmaxf(rmax[r], __shfl_xor(rmax[r], dd));
    if (ln == 0) {
#pragma unroll
        for (int r = 0; r < 4; ++r) red[sh * 32 + rowb + r] = rmax[r];
    }
    __syncthreads();
    if (tid < 32)
        wsrow[(size_t)b * T_DIM + t0 + tid] = fmaxf(red[tid], red[32 + tid]);
}

// out[b] = sum_t ws[b][t]
__global__ void reduce_b(const float* __restrict__ ws, float* __restrict__ out)
{
    const int b = blockIdx.x;
    float s = 0.f;
    for (int t = threadIdx.x; t < T_DIM; t += 256) s += ws[(size_t)b * T_DIM + t];
#pragma unroll
    for (int dd = 32; dd > 0; dd >>= 1) s += __shfl_xor(s, dd);
    __shared__ float acc[4];
    if ((threadIdx.x & 63) == 0) acc[threadIdx.x >> 6] = s;
    __syncthreads();
    if (threadIdx.x == 0) out[b] = acc[0] + acc[1] + acc[2] + acc[3];
}

extern "C" void kernel_launch(void* const* d_in, const int* in_sizes, int n_in,
                              void* d_out, int out_size, void* d_ws, size_t ws_size,
                              hipStream_t stream)
{
    const float* Q    = (const float*)d_in[0];
    const float* K    = (const float*)d_in[1];
    const float* V    = (const float*)d_in[2];
    const float* Mask = (const float*)d_in[3];
    const int*   m    = (const int*)d_in[4];
    float* out = (float*)d_out;

    const size_t frag_bytes = (size_t)B_DIM * T_DIM * C_DIM * 2;   // 33,554,432 per tensor
    const size_t need_main  = 3 * frag_bytes + (size_t)B_DIM * T_DIM * 4;

    if (ws_size >= need_main) {
        unsigned short* Qt  = (unsigned short*)d_ws;
        unsigned short* Kt  = (unsigned short*)((char*)d_ws + frag_bytes);
        unsigned short* Vtt = (unsigned short*)((char*)d_ws + 2 * frag_bytes);
        float* wsrow = (float*)((char*)d_ws + 3 * frag_bytes);
        prep_qkv<<<dim3(640, B_DIM), 256, 0, stream>>>(Q, K, V, Qt, Kt, Vtt);
        attn_band_tiled<<<dim3((T_DIM / TB) * B_DIM), 256, 0, stream>>>(Qt, Kt, Vtt, Mask, m, wsrow);
        reduce_b<<<B_DIM, 256, 0, stream>>>(wsrow, out);
    } else {
        unsigned short* Vt = (unsigned short*)d_ws;
        float* wsrow = (float*)((char*)d_ws + frag_bytes);
        transpose_vx<<<dim3(T_DIM / 64, C_DIM / 64, B_DIM), 256, 0, stream>>>(V, Vt, 0);
        attn_band_mfma<<<dim3((T_DIM / TB) * B_DIM), 256, 0, stream>>>(Q, K, Vt, Mask, m, wsrow);
        reduce_b<<<B_DIM, 256, 0, stream>>>(wsrow, out);
    }
}

// Round 12
// 104.277 us; speedup vs baseline: 1.8796x; 1.0609x over previous
//
#include <hip/hip_runtime.h>
#include <math.h>

#define T_DIM 2048
#define C_DIM 1024
#define B_DIM 8
#define TB    32
#define KROW  72      // bf16 elems per Kc/Qc row (64 + 8 pad)  [fallback kernel]
#define PROW  296     // bf16 elems per P row (288 + 8 pad)

typedef float f32x4 __attribute__((ext_vector_type(4)));
typedef short s16x8 __attribute__((ext_vector_type(8)));

__device__ __forceinline__ unsigned short f2bf(float x) {
    union { float f; unsigned u; } v; v.f = x;
    unsigned r = v.u + 0x7fffu + ((v.u >> 16) & 1u);
    return (unsigned short)(r >> 16);
}
__device__ __forceinline__ unsigned pk2(float a, float b) {
    return (unsigned)f2bf(a) | ((unsigned)f2bf(b) << 16);
}

// async 16B/lane global->LDS DMA. LDS dest = wave-uniform base + lane*16 (linear);
// global SOURCE is per-lane (m173) -> can gather scattered 16B chunks into linear LDS.
__device__ __forceinline__ void gll16(const void* g, void* l) {
    __builtin_amdgcn_global_load_lds(
        (const __attribute__((address_space(1))) unsigned int*)g,
        (__attribute__((address_space(3))) unsigned int*)l,
        16, 0, 0);
}

// ============ pre-pass A: K f32 -> bf16, row-major preserved (pure stream, r4-verified) ============
// grid (1024, B), 256 thr; block converts 2048 contiguous elems (8/thread)
__global__ __launch_bounds__(256)
void conv_k(const float* __restrict__ K, unsigned short* __restrict__ Kb)
{
    const size_t base = (size_t)blockIdx.y * T_DIM * C_DIM
                      + (size_t)blockIdx.x * 2048 + (size_t)threadIdx.x * 8;
    const float4* src = (const float4*)(K + base);
    float4 x = src[0], y = src[1];
    uint4 o;
    o.x = pk2(x.x, x.y); o.y = pk2(x.z, x.w);
    o.z = pk2(y.x, y.y); o.w = pk2(y.z, y.w);
    *(uint4*)(Kb + base) = o;
}

// ============ pre-pass B: V f32 -> bf16, fragment-major Vtt OR row-major Vt (verified) ============
// frag_mode=1: Vtt[b][ct][sg][lane][8], elem = V[b][sg*32+(l>>4)*8+j][ct*16+(l&15)]
__global__ __launch_bounds__(256)
void transpose_vx(const float* __restrict__ V, unsigned short* __restrict__ out,
                  int frag_mode)
{
    __shared__ float buf[64 * 67];
    const int t0 = blockIdx.x * 64;
    const int c0 = blockIdx.y * 64;
    const int b  = blockIdx.z;
    const float* Vb = V + (size_t)b * T_DIM * C_DIM;

    for (int i = threadIdx.x; i < 64 * 64; i += 256) {
        const int r = i >> 6, c = i & 63;
        buf[r * 67 + c] = Vb[(size_t)(t0 + r) * C_DIM + c0 + c];
    }
    __syncthreads();
    const int t8 = threadIdx.x & 7;   // 8-t segment
    const int cl = threadIdx.x >> 3;  // 0..31
#pragma unroll
    for (int half = 0; half < 2; ++half) {
        const int c_loc = cl + half * 32;
        float v[8];
#pragma unroll
        for (int j = 0; j < 8; ++j) v[j] = buf[(t8 * 8 + j) * 67 + c_loc];
        uint4 o;
        o.x = pk2(v[0], v[1]); o.y = pk2(v[2], v[3]);
        o.z = pk2(v[4], v[5]); o.w = pk2(v[6], v[7]);
        if (frag_mode) {
            const int ct = (c0 + c_loc) >> 4, lnv = c_loc & 15;
            const int g = t8 & 3, sg = (t0 >> 5) + (t8 >> 2);
            *(uint4*)(out + (size_t)(((b * 64 + ct) * 64 + sg) * 64 + g * 16 + lnv) * 8) = o;
        } else {
            *(uint4*)(out + (size_t)(b * C_DIM + c0 + c_loc) * T_DIM + t0 + t8 * 8) = o;
        }
    }
}

// ============ banded attention: per-lane-source gll16 from row-major bf16 K + f32 Q ============
// 256 thr = 4 waves (th = t-half of 32-row tile, sh = s-half / c-split).
// Phase 1: per kk stage 18 K frags (gathered from row-major Kb) + 2 Q f32 tiles (4 slots),
//          double-buffered, 1 barrier/iter.  Phase 3: verified r8 structure (Vtt frag-major).
__global__ __launch_bounds__(256, 2)
void attn_band_tiled(const float* __restrict__ Q,
                     const unsigned short* __restrict__ Kb,
                     const unsigned short* __restrict__ Vtt,
                     const float* __restrict__ Mask, const int* __restrict__ m_ptr,
                     float* __restrict__ wsrow)
{
    // byte map: phase1: Kbuf = [0, 36864) (2 x 18 frags x 1KB), Qbuf = [36864, 45056) (2 x 4KB)
    //           phase2/3: P = [0, 18944); Vbuf = [19456, 60416) (2 x 20 x 1KB)
    // RAW must cover the PHASE-3 extent too: 60,416 B (r11 bug: was 45,056 -> Vbuf overflow)
    __shared__ __align__(16) char RAW[60416];
    __shared__ float pmax[64], psum[64], red[64];
    short* P = (short*)RAW;

    // XCD-bijective swizzle: each XCD owns one batch's contiguous t-range
    const int h = blockIdx.x;
    const int logical = (h & 7) * 64 + (h >> 3);
    const int b  = logical >> 6;
    const int t0 = (logical & 63) * TB;

    const int tid = threadIdx.x;
    const int w = tid >> 6, lane = tid & 63, g = lane >> 4, ln = lane & 15;
    const int th = w >> 1, sh = w & 1;
    const int m  = m_ptr[0];

    const int s_lo = max(0, t0 - m);
    const int s_hi = min(T_DIM - 1, t0 + TB - 1 + m);
    const int sg0  = s_lo >> 5;               // 32-aligned by construction

    const float*          Qg  = Q   + (size_t)b * T_DIM * C_DIM;
    const unsigned short* Kg  = Kb  + (size_t)b * T_DIM * C_DIM;
    const unsigned short* Vtb = Vtt + (size_t)b * 64 * 64 * 512;

    // ---- phase 1: E = Q.K^T ----
    f32x4 E[9];
    f32x4 zed = {0.f, 0.f, 0.f, 0.f};
#pragma unroll
    for (int i = 0; i < 9; ++i) E[i] = zed;

    // wave w: K frags f = 5w..5w+4 (f<18), gathered per-lane from row-major Kb;
    //         plus one Q f32 call: tile tt=w>>1, half hh=w&1 (4 slots x 1KB, lane-linear).
#define STAGE1(KN, NB)                                                               \
    {                                                                                \
        short* kd = (short*)(RAW) + (NB) * 9216;                                     \
        _Pragma("unroll")                                                            \
        for (int f5 = 0; f5 < 5; ++f5) {                                             \
            const int f = w * 5 + f5;                                                \
            if (f < 18) {                                                            \
                const int row = min(sg0 * 2 + f, 127) * 16 + ln;                     \
                gll16(Kg + (size_t)row * C_DIM + (KN) * 32 + g * 8, kd + f * 512);   \
            }                                                                        \
        }                                                                            \
        {                                                                            \
            const int tt = w >> 1, hh = w & 1;                                       \
            const float* qs = Qg + (size_t)(t0 + tt * 16 + ln) * C_DIM               \
                                 + (KN) * 32 + g * 8 + hh * 4;                       \
            gll16(qs, (float*)(RAW + 36864) + (NB) * 1024 + (tt * 2 + hh) * 256);    \
        }                                                                            \
    }

    STAGE1(0, 0);
    __syncthreads();

#pragma unroll 2
    for (int kk = 0; kk < 32; ++kk) {
        const int cur = kk & 1;
        if (kk < 31) STAGE1(kk + 1, cur ^ 1);
        const short* cb = (const short*)(RAW) + cur * 9216;
        const float* qb = (const float*)(RAW + 36864) + cur * 1024;
        f32x4 qlo = *(const f32x4*)(qb + (th * 2    ) * 256 + lane * 4);
        f32x4 qhi = *(const f32x4*)(qb + (th * 2 + 1) * 256 + lane * 4);
        uint4 aqi;
        aqi.x = pk2(qlo[0], qlo[1]); aqi.y = pk2(qlo[2], qlo[3]);
        aqi.z = pk2(qhi[0], qhi[1]); aqi.w = pk2(qhi[2], qhi[3]);
        s16x8 aq = *(s16x8*)&aqi;
#pragma unroll
        for (int i = 0; i < 9; ++i) {
            s16x8 bk = *(const s16x8*)(cb + (sh * 9 + i) * 512 + lane * 8);
            E[i] = __builtin_amdgcn_mfma_f32_16x16x32_bf16(aq, bk, E[i], 0, 0, 0);
        }
        __syncthreads();
    }

    // ---- phase 2: exact softmax (cross-wave over the two s-halves) ----
    const float scale = 0.03125f;   // 1/sqrt(1024)
    const int rowb = th * 16 + g * 4;
    float lm[4];
#pragma unroll
    for (int r = 0; r < 4; ++r) lm[r] = -INFINITY;
    const int s_base = s_lo + sh * 144 + ln;
#pragma unroll
    for (int i = 0; i < 9; ++i) {
        const int s = s_base + i * 16;
#pragma unroll
        for (int r = 0; r < 4; ++r) {
            const int t = t0 + rowb + r;
            int d = t - s; d = d < 0 ? -d : d;
            const bool valid = (s <= s_hi) && (d <= m);
            float e = valid ? E[i][r] : -INFINITY;
            E[i][r] = e;
            lm[r] = fmaxf(lm[r], e);
        }
    }
#pragma unroll
    for (int r = 0; r < 4; ++r)
#pragma unroll
        for (int dd = 1; dd < 16; dd <<= 1) lm[r] = fmaxf(lm[r], __shfl_xor(lm[r], dd));
    if (ln == 0) {
#pragma unroll
        for (int r = 0; r < 4; ++r) pmax[sh * 32 + rowb + r] = lm[r];
    }
    __syncthreads();
    float Mr[4], sum[4];
#pragma unroll
    for (int r = 0; r < 4; ++r) {
        Mr[r] = fmaxf(pmax[rowb + r], pmax[32 + rowb + r]) * scale;
        sum[r] = 0.f;
    }
#pragma unroll
    for (int i = 0; i < 9; ++i)
#pragma unroll
        for (int r = 0; r < 4; ++r) {
            float e = __expf(E[i][r] * scale - Mr[r]);   // -inf -> 0 exactly
            E[i][r] = e;
            sum[r] += e;
        }
#pragma unroll
    for (int r = 0; r < 4; ++r)
#pragma unroll
        for (int dd = 1; dd < 16; dd <<= 1) sum[r] += __shfl_xor(sum[r], dd);
    if (ln == 0) {
#pragma unroll
        for (int r = 0; r < 4; ++r) psum[sh * 32 + rowb + r] = sum[r];
    }
    __syncthreads();
    float inv[4];
#pragma unroll
    for (int r = 0; r < 4; ++r) inv[r] = 1.0f / (psum[rowb + r] + psum[32 + rowb + r]);
#pragma unroll
    for (int i = 0; i < 9; ++i) {
        const int col = sh * 144 + i * 16 + ln;
#pragma unroll
        for (int r = 0; r < 4; ++r)
            P[(rowb + r) * PROW + col] = (short)f2bf(E[i][r] * inv[r]);
    }
    __syncthreads();

    // ---- phase 3: O = P @ V; per q two staged steps (kg 0-4, 5-8), dbuf, 1 barrier/step ----
    short* Vbuf = (short*)(RAW + 19456);
    s16x8 pa[9];
#pragma unroll
    for (int kg = 0; kg < 9; ++kg)
        pa[kg] = *(const s16x8*)(P + (th * 16 + ln) * PROW + kg * 32 + g * 8);

    int sgc[9];
#pragma unroll
    for (int kg = 0; kg < 9; ++kg) sgc[kg] = min(sg0 + kg, 63);

    float maskv[4], rmax[4];
#pragma unroll
    for (int r = 0; r < 4; ++r) {
        maskv[r] = Mask[(size_t)b * T_DIM + t0 + rowb + r];
        rmax[r]  = -INFINITY;
    }

    // wave w stages ct = 4q+w, kg in [kgbase, kgbase+KG): slot (w*KG + e)
#define STAGE3(S, NB)                                                               \
    {                                                                               \
        const int q_ = (S) >> 1;                                                    \
        short* dstb = Vbuf + (NB) * 10240;                                          \
        const int ct_ = q_ * 4 + w;                                                 \
        if (((S) & 1) == 0) {                                                       \
            _Pragma("unroll")                                                       \
            for (int e = 0; e < 5; ++e)                                             \
                gll16(Vtb + ((size_t)(ct_ * 64 + sgc[e]) * 64 + lane) * 8,          \
                      dstb + (w * 5 + e) * 512);                                    \
        } else {                                                                    \
            _Pragma("unroll")                                                       \
            for (int e = 0; e < 4; ++e)                                             \
                gll16(Vtb + ((size_t)(ct_ * 64 + sgc[5 + e]) * 64 + lane) * 8,      \
                      dstb + (w * 4 + e) * 512);                                    \
        }                                                                           \
    }

    STAGE3(0, 0);
    __syncthreads();

    f32x4 O0 = zed, O1 = zed;
#pragma unroll 2
    for (int s = 0; s < 32; ++s) {
        const int cur = s & 1;
        if (s < 31) STAGE3(s + 1, cur ^ 1);
        const short* vb = Vbuf + cur * 10240;
        if ((s & 1) == 0) {
            O0 = zed; O1 = zed;
#pragma unroll
            for (int e = 0; e < 5; ++e) {
                s16x8 bv0 = *(const s16x8*)(vb + ((sh * 2    ) * 5 + e) * 512 + lane * 8);
                s16x8 bv1 = *(const s16x8*)(vb + ((sh * 2 + 1) * 5 + e) * 512 + lane * 8);
                O0 = __builtin_amdgcn_mfma_f32_16x16x32_bf16(pa[e], bv0, O0, 0, 0, 0);
                O1 = __builtin_amdgcn_mfma_f32_16x16x32_bf16(pa[e], bv1, O1, 0, 0, 0);
            }
        } else {
#pragma unroll
            for (int e = 0; e < 4; ++e) {
                s16x8 bv0 = *(const s16x8*)(vb + ((sh * 2    ) * 4 + e) * 512 + lane * 8);
                s16x8 bv1 = *(const s16x8*)(vb + ((sh * 2 + 1) * 4 + e) * 512 + lane * 8);
                O0 = __builtin_amdgcn_mfma_f32_16x16x32_bf16(pa[5 + e], bv0, O0, 0, 0, 0);
                O1 = __builtin_amdgcn_mfma_f32_16x16x32_bf16(pa[5 + e], bv1, O1, 0, 0, 0);
            }
#pragma unroll
            for (int r = 0; r < 4; ++r) {
                rmax[r] = fmaxf(rmax[r], O0[r] * maskv[r]);
                rmax[r] = fmaxf(rmax[r], O1[r] * maskv[r]);
            }
        }
        __syncthreads();
    }

#pragma unroll
    for (int r = 0; r < 4; ++r)
#pragma unroll
        for (int dd = 1; dd < 16; dd <<= 1) rmax[r] = fmaxf(rmax[r], __shfl_xor(rmax[r], dd));
    if (ln == 0) {
#pragma unroll
        for (int r = 0; r < 4; ++r) red[sh * 32 + rowb + r] = rmax[r];
    }
    __syncthreads();
    if (tid < 32)
        wsrow[(size_t)b * T_DIM + t0 + tid] = fmaxf(red[tid], red[32 + tid]);
}

// ============ fallback (round-1, verified): K/V staged per block, Vt row-major ============
__global__ __launch_bounds__(256, 2)
void attn_band_mfma(const float* __restrict__ Q, const float* __restrict__ K,
                    const unsigned short* __restrict__ Vt,
                    const float* __restrict__ Mask, const int* __restrict__ m_ptr,
                    float* __restrict__ wsrow)
{
    __shared__ __align__(16) char smem_raw[57600];
    short* SM = (short*)smem_raw;
    short* Kc = SM;
    short* Qc = SM + 288 * KROW;
    short* P  = SM;
    short* Vl = SM + 32 * PROW;
    float* pmax = (float*)(smem_raw + 56832);
    float* psum = pmax + 64;
    float* red  = psum + 64;

    const int h = blockIdx.x;
    const int logical = (h & 7) * 64 + (h >> 3);
    const int b  = logical >> 6;
    const int t0 = (logical & 63) * TB;

    const int tid = threadIdx.x;
    const int w = tid >> 6, lane = tid & 63, g = lane >> 4, ln = lane & 15;
    const int th = w >> 1, sh = w & 1;
    const int m  = m_ptr[0];

    const int s_lo = max(0, t0 - m);
    const int s_hi = min(T_DIM - 1, t0 + TB - 1 + m);

    const float* Qb = Q + (size_t)b * T_DIM * C_DIM;
    const float* Kb = K + (size_t)b * T_DIM * C_DIM;
    const unsigned short* Vtb = Vt + (size_t)b * C_DIM * T_DIM;

    f32x4 E[9];
    f32x4 zed = {0.f, 0.f, 0.f, 0.f};
#pragma unroll
    for (int i = 0; i < 9; ++i) E[i] = zed;

    for (int cc = 0; cc < C_DIM / 64; ++cc) {
        const int c0 = cc * 64;
        __syncthreads();
        for (int u = tid; u < 288 * 8; u += 256) {
            const int su = u >> 3, un = u & 7;
            const int s = min(s_lo + su, T_DIM - 1);
            const float4* src = (const float4*)(Kb + (size_t)s * C_DIM + c0 + un * 8);
            float4 x = src[0], y = src[1];
            uint4 o; o.x = pk2(x.x, x.y); o.y = pk2(x.z, x.w);
            o.z = pk2(y.x, y.y); o.w = pk2(y.z, y.w);
            *(uint4*)(Kc + su * KROW + un * 8) = o;
        }
        {
            const int su = tid >> 3, un = tid & 7;
            const float4* src = (const float4*)(Qb + (size_t)(t0 + su) * C_DIM + c0 + un * 8);
            float4 x = src[0], y = src[1];
            uint4 o; o.x = pk2(x.x, x.y); o.y = pk2(x.z, x.w);
            o.z = pk2(y.x, y.y); o.w = pk2(y.z, y.w);
            *(uint4*)(Qc + su * KROW + un * 8) = o;
        }
        __syncthreads();
        s16x8 aq[2];
#pragma unroll
        for (int kk = 0; kk < 2; ++kk)
            aq[kk] = *(const s16x8*)(Qc + (th * 16 + ln) * KROW + kk * 32 + g * 8);
#pragma unroll
        for (int i = 0; i < 9; ++i) {
            const int srow2 = (sh * 9 + i) * 16 + ln;
#pragma unroll
            for (int kk = 0; kk < 2; ++kk) {
                s16x8 bk = *(const s16x8*)(Kc + srow2 * KROW + kk * 32 + g * 8);
                E[i] = __builtin_amdgcn_mfma_f32_16x16x32_bf16(aq[kk], bk, E[i], 0, 0, 0);
            }
        }
    }

    const float scale = 0.03125f;
    const int rowb = th * 16 + g * 4;
    float lm[4];
#pragma unroll
    for (int r = 0; r < 4; ++r) lm[r] = -INFINITY;
    const int s_base = s_lo + sh * 144 + ln;
#pragma unroll
    for (int i = 0; i < 9; ++i) {
        const int s = s_base + i * 16;
#pragma unroll
        for (int r = 0; r < 4; ++r) {
            const int t = t0 + rowb + r;
            int d = t - s; d = d < 0 ? -d : d;
            const bool valid = (s <= s_hi) && (d <= m);
            float e = valid ? E[i][r] : -INFINITY;
            E[i][r] = e;
            lm[r] = fmaxf(lm[r], e);
        }
    }
#pragma unroll
    for (int r = 0; r < 4; ++r)
#pragma unroll
        for (int dd = 1; dd < 16; dd <<= 1) lm[r] = fmaxf(lm[r], __shfl_xor(lm[r], dd));
    if (ln == 0) {
#pragma unroll
        for (int r = 0; r < 4; ++r) pmax[sh * 32 + rowb + r] = lm[r];
    }
    __syncthreads();
    float Mr[4], sum[4];
#pragma unroll
    for (int r = 0; r < 4; ++r) {
        Mr[r] = fmaxf(pmax[rowb + r], pmax[32 + rowb + r]) * scale;
        sum[r] = 0.f;
    }
#pragma unroll
    for (int i = 0; i < 9; ++i)
#pragma unroll
        for (int r = 0; r < 4; ++r) {
            float e = __expf(E[i][r] * scale - Mr[r]);
            E[i][r] = e;
            sum[r] += e;
        }
#pragma unroll
    for (int r = 0; r < 4; ++r)
#pragma unroll
        for (int dd = 1; dd < 16; dd <<= 1) sum[r] += __shfl_xor(sum[r], dd);
    if (ln == 0) {
#pragma unroll
        for (int r = 0; r < 4; ++r) psum[sh * 32 + rowb + r] = sum[r];
    }
    __syncthreads();
    float inv[4];
#pragma unroll
    for (int r = 0; r < 4; ++r) inv[r] = 1.0f / (psum[rowb + r] + psum[32 + rowb + r]);
#pragma unroll
    for (int i = 0; i < 9; ++i) {
        const int col = sh * 144 + i * 16 + ln;
#pragma unroll
        for (int r = 0; r < 4; ++r)
            P[(rowb + r) * PROW + col] = (short)f2bf(E[i][r] * inv[r]);
    }
    __syncthreads();

    s16x8 pa[9];
#pragma unroll
    for (int kg = 0; kg < 9; ++kg)
        pa[kg] = *(const s16x8*)(P + (th * 16 + ln) * PROW + kg * 32 + g * 8);

    float maskv[4], rmax[4];
#pragma unroll
    for (int r = 0; r < 4; ++r) {
        maskv[r] = Mask[(size_t)b * T_DIM + t0 + rowb + r];
        rmax[r]  = -INFINITY;
    }

    for (int cc = 0; cc < C_DIM / 64; ++cc) {
        __syncthreads();
        for (int i2 = tid; i2 < 64 * 36; i2 += 256) {
            const int cr = i2 / 36, un = i2 - cr * 36;
            const int sb = min(s_lo + un * 8, T_DIM - 8);
            uint4 x = *(const uint4*)(Vtb + (size_t)(cc * 64 + cr) * T_DIM + sb);
            *(uint4*)(Vl + cr * PROW + un * 8) = x;
        }
        __syncthreads();
#pragma unroll
        for (int nbi = 0; nbi < 2; ++nbi) {
            const int crow = sh * 32 + nbi * 16 + ln;
            f32x4 O = zed;
#pragma unroll
            for (int kg = 0; kg < 9; ++kg) {
                s16x8 bv = *(const s16x8*)(Vl + crow * PROW + kg * 32 + g * 8);
                O = __builtin_amdgcn_mfma_f32_16x16x32_bf16(pa[kg], bv, O, 0, 0, 0);
            }
#pragma unroll
            for (int r = 0; r < 4; ++r)
                rmax[r] = fmaxf(rmax[r], O[r] * maskv[r]);
        }
    }
#pragma unroll
    for (int r = 0; r < 4; ++r)
#pragma unroll
        for (int dd = 1; dd < 16; dd <<= 1) rmax[r] = fmaxf(rmax[r], __shfl_xor(rmax[r], dd));
    if (ln == 0) {
#pragma unroll
        for (int r = 0; r < 4; ++r) red[sh * 32 + rowb + r] = rmax[r];
    }
    __syncthreads();
    if (tid < 32)
        wsrow[(size_t)b * T_DIM + t0 + tid] = fmaxf(red[tid], red[32 + tid]);
}

// out[b] = sum_t ws[b][t]
__global__ void reduce_b(const float* __restrict__ ws, float* __restrict__ out)
{
    const int b = blockIdx.x;
    float s = 0.f;
    for (int t = threadIdx.x; t < T_DIM; t += 256) s += ws[(size_t)b * T_DIM + t];
#pragma unroll
    for (int dd = 32; dd > 0; dd >>= 1) s += __shfl_xor(s, dd);
    __shared__ float acc[4];
    if ((threadIdx.x & 63) == 0) acc[threadIdx.x >> 6] = s;
    __syncthreads();
    if (threadIdx.x == 0) out[b] = acc[0] + acc[1] + acc[2] + acc[3];
}

extern "C" void kernel_launch(void* const* d_in, const int* in_sizes, int n_in,
                              void* d_out, int out_size, void* d_ws, size_t ws_size,
                              hipStream_t stream)
{
    const float* Q    = (const float*)d_in[0];
    const float* K    = (const float*)d_in[1];
    const float* V    = (const float*)d_in[2];
    const float* Mask = (const float*)d_in[3];
    const int*   m    = (const int*)d_in[4];
    float* out = (float*)d_out;

    const size_t frag_bytes = (size_t)B_DIM * T_DIM * C_DIM * 2;   // 33,554,432 per tensor
    const size_t need_main  = 2 * frag_bytes + (size_t)B_DIM * T_DIM * 4;

    if (ws_size >= need_main) {
        unsigned short* Kb  = (unsigned short*)d_ws;
        unsigned short* Vtt = (unsigned short*)((char*)d_ws + frag_bytes);
        float* wsrow = (float*)((char*)d_ws + 2 * frag_bytes);
        conv_k<<<dim3(1024, B_DIM), 256, 0, stream>>>(K, Kb);
        transpose_vx<<<dim3(T_DIM / 64, C_DIM / 64, B_DIM), 256, 0, stream>>>(V, Vtt, 1);
        attn_band_tiled<<<dim3((T_DIM / TB) * B_DIM), 256, 0, stream>>>(Q, Kb, Vtt, Mask, m, wsrow);
        reduce_b<<<B_DIM, 256, 0, stream>>>(wsrow, out);
    } else {
        unsigned short* Vt = (unsigned short*)d_ws;
        float* wsrow = (float*)((char*)d_ws + frag_bytes);
        transpose_vx<<<dim3(T_DIM / 64, C_DIM / 64, B_DIM), 256, 0, stream>>>(V, Vt, 0);
        attn_band_mfma<<<dim3((T_DIM / TB) * B_DIM), 256, 0, stream>>>(Q, K, Vt, Mask, m, wsrow);
        reduce_b<<<B_DIM, 256, 0, stream>>>(wsrow, out);
    }
}

// Round 13
// 100.968 us; speedup vs baseline: 1.9412x; 1.0328x over previous
//
#include <hip/hip_runtime.h>
#include <math.h>

#define T_DIM 2048
#define C_DIM 1024
#define B_DIM 8
#define TB    32
#define KROW  72      // bf16 elems per Kc/Qc row (64 + 8 pad)  [fallback kernel]
#define PROW  296     // bf16 elems per P row (288 + 8 pad)

typedef float f32x4 __attribute__((ext_vector_type(4)));
typedef short s16x8 __attribute__((ext_vector_type(8)));

__device__ __forceinline__ unsigned short f2bf(float x) {
    union { float f; unsigned u; } v; v.f = x;
    unsigned r = v.u + 0x7fffu + ((v.u >> 16) & 1u);
    return (unsigned short)(r >> 16);
}
__device__ __forceinline__ unsigned pk2(float a, float b) {
    return (unsigned)f2bf(a) | ((unsigned)f2bf(b) << 16);
}

// async 16B/lane global->LDS DMA. LDS dest = wave-uniform base + lane*16 (linear);
// global SOURCE is per-lane.
__device__ __forceinline__ void gll16(const void* g, void* l) {
    __builtin_amdgcn_global_load_lds(
        (const __attribute__((address_space(1))) unsigned int*)g,
        (__attribute__((address_space(3))) unsigned int*)l,
        16, 0, 0);
}

// ============ pre-pass A: K f32 -> fragment-major bf16 Kt[b][tile][kk][lane][8] ============
// elem = K[b][tile*16+(l&15)][kk*32+(l>>4)*8+j]  [r5-verified]
__global__ __launch_bounds__(256)
void tile_k(const float* __restrict__ K, unsigned short* __restrict__ Kt)
{
    const int tile = blockIdx.x;      // 0..127
    const int b    = blockIdx.y;
    const int tid  = threadIdx.x;
    const int w = tid >> 6, l = tid & 63, g = l >> 4, ln = l & 15;
    const float* src_row = K + (size_t)(b * T_DIM + tile * 16 + ln) * C_DIM;
#pragma unroll
    for (int kki = 0; kki < 8; ++kki) {
        const int kk = kki * 4 + w;
        const float4* p = (const float4*)(src_row + kk * 32 + g * 8);
        float4 x = p[0], y = p[1];
        uint4 o;
        o.x = pk2(x.x, x.y); o.y = pk2(x.z, x.w);
        o.z = pk2(y.x, y.y); o.w = pk2(y.z, y.w);
        *(uint4*)(Kt + (size_t)(((b * 128 + tile) * 32 + kk) * 64 + l) * 8) = o;
    }
}

// ============ pre-pass B: V f32 -> bf16, fragment-major Vtt OR row-major Vt (verified) ============
__global__ __launch_bounds__(256)
void transpose_vx(const float* __restrict__ V, unsigned short* __restrict__ out,
                  int frag_mode)
{
    __shared__ float buf[64 * 67];
    const int t0 = blockIdx.x * 64;
    const int c0 = blockIdx.y * 64;
    const int b  = blockIdx.z;
    const float* Vb = V + (size_t)b * T_DIM * C_DIM;

    for (int i = threadIdx.x; i < 64 * 64; i += 256) {
        const int r = i >> 6, c = i & 63;
        buf[r * 67 + c] = Vb[(size_t)(t0 + r) * C_DIM + c0 + c];
    }
    __syncthreads();
    const int t8 = threadIdx.x & 7;   // 8-t segment
    const int cl = threadIdx.x >> 3;  // 0..31
#pragma unroll
    for (int half = 0; half < 2; ++half) {
        const int c_loc = cl + half * 32;
        float v[8];
#pragma unroll
        for (int j = 0; j < 8; ++j) v[j] = buf[(t8 * 8 + j) * 67 + c_loc];
        uint4 o;
        o.x = pk2(v[0], v[1]); o.y = pk2(v[2], v[3]);
        o.z = pk2(v[4], v[5]); o.w = pk2(v[6], v[7]);
        if (frag_mode) {
            const int ct = (c0 + c_loc) >> 4, lnv = c_loc & 15;
            const int g = t8 & 3, sg = (t0 >> 5) + (t8 >> 2);
            *(uint4*)(out + (size_t)(((b * 64 + ct) * 64 + sg) * 64 + g * 16 + lnv) * 8) = o;
        } else {
            *(uint4*)(out + (size_t)(b * C_DIM + c0 + c_loc) * T_DIM + t0 + t8 * 8) = o;
        }
    }
}

// ============ banded attention: Kt fragment-major (contiguous DMA, r8) + Q f32 (r12) ============
// 256 thr = 4 waves (th = t-half of 32-row tile, sh = s-half / c-split).
__global__ __launch_bounds__(256, 2)
void attn_band_tiled(const float* __restrict__ Q,
                     const unsigned short* __restrict__ Kt,
                     const unsigned short* __restrict__ Vtt,
                     const float* __restrict__ Mask, const int* __restrict__ m_ptr,
                     float* __restrict__ wsrow)
{
    // byte map: phase1: Kbuf = [0, 36864) (2 x 18 frags x 1KB), Qbuf = [36864, 45056) (2 x 4KB)
    //           phase2/3: P = [0, 18944); Vbuf = [19456, 60416) (2 x 20 x 1KB)
    __shared__ __align__(16) char RAW[60416];
    __shared__ float pmax[64], psum[64], red[64];
    short* P = (short*)RAW;

    // XCD-bijective swizzle: each XCD owns one batch's contiguous t-range
    const int h = blockIdx.x;
    const int logical = (h & 7) * 64 + (h >> 3);
    const int b  = logical >> 6;
    const int t0 = (logical & 63) * TB;

    const int tid = threadIdx.x;
    const int w = tid >> 6, lane = tid & 63, g = lane >> 4, ln = lane & 15;
    const int th = w >> 1, sh = w & 1;
    const int m  = m_ptr[0];

    const int s_lo = max(0, t0 - m);
    const int s_hi = min(T_DIM - 1, t0 + TB - 1 + m);
    const int sg0  = s_lo >> 5;               // 32-aligned by construction

    const float*          Qg  = Q   + (size_t)b * T_DIM * C_DIM;
    const unsigned short* Ktb = Kt  + (size_t)b * 128 * 32 * 512;
    const unsigned short* Vtb = Vtt + (size_t)b * 64 * 64 * 512;

    // ---- phase 1: E = Q.K^T ----
    f32x4 E[9];
    f32x4 zed = {0.f, 0.f, 0.f, 0.f};
#pragma unroll
    for (int i = 0; i < 9; ++i) E[i] = zed;

    // wave w: K frags f = 5w..5w+4 (f<18) CONTIGUOUS from fragment-major Kt (r8 pattern);
    //         plus one Q f32 call: tile tt=w>>1, half hh=w&1 (4 slots x 1KB, lane-linear, r12).
#define STAGE1(KN, NB)                                                               \
    {                                                                                \
        short* kd = (short*)(RAW) + (NB) * 9216;                                     \
        _Pragma("unroll")                                                            \
        for (int f5 = 0; f5 < 5; ++f5) {                                             \
            const int f = w * 5 + f5;                                                \
            if (f < 18) {                                                            \
                const int ktile = min(sg0 * 2 + f, 127);                             \
                gll16(Ktb + ((size_t)(ktile * 32 + (KN)) * 64 + lane) * 8,           \
                      kd + f * 512);                                                 \
            }                                                                        \
        }                                                                            \
        {                                                                            \
            const int tt = w >> 1, hh = w & 1;                                       \
            const float* qs = Qg + (size_t)(t0 + tt * 16 + ln) * C_DIM               \
                                 + (KN) * 32 + g * 8 + hh * 4;                       \
            gll16(qs, (float*)(RAW + 36864) + (NB) * 1024 + (tt * 2 + hh) * 256);    \
        }                                                                            \
    }

    STAGE1(0, 0);
    __syncthreads();

#pragma unroll 2
    for (int kk = 0; kk < 32; ++kk) {
        const int cur = kk & 1;
        if (kk < 31) STAGE1(kk + 1, cur ^ 1);
        const short* cb = (const short*)(RAW) + cur * 9216;
        const float* qb = (const float*)(RAW + 36864) + cur * 1024;
        f32x4 qlo = *(const f32x4*)(qb + (th * 2    ) * 256 + lane * 4);
        f32x4 qhi = *(const f32x4*)(qb + (th * 2 + 1) * 256 + lane * 4);
        uint4 aqi;
        aqi.x = pk2(qlo[0], qlo[1]); aqi.y = pk2(qlo[2], qlo[3]);
        aqi.z = pk2(qhi[0], qhi[1]); aqi.w = pk2(qhi[2], qhi[3]);
        s16x8 aq = *(s16x8*)&aqi;
#pragma unroll
        for (int i = 0; i < 9; ++i) {
            s16x8 bk = *(const s16x8*)(cb + (sh * 9 + i) * 512 + lane * 8);
            E[i] = __builtin_amdgcn_mfma_f32_16x16x32_bf16(aq, bk, E[i], 0, 0, 0);
        }
        __syncthreads();
    }

    // ---- phase 2: exact softmax (cross-wave over the two s-halves) ----
    const float scale = 0.03125f;   // 1/sqrt(1024)
    const int rowb = th * 16 + g * 4;
    float lm[4];
#pragma unroll
    for (int r = 0; r < 4; ++r) lm[r] = -INFINITY;
    const int s_base = s_lo + sh * 144 + ln;
#pragma unroll
    for (int i = 0; i < 9; ++i) {
        const int s = s_base + i * 16;
#pragma unroll
        for (int r = 0; r < 4; ++r) {
            const int t = t0 + rowb + r;
            int d = t - s; d = d < 0 ? -d : d;
            const bool valid = (s <= s_hi) && (d <= m);
            float e = valid ? E[i][r] : -INFINITY;
            E[i][r] = e;
            lm[r] = fmaxf(lm[r], e);
        }
    }
#pragma unroll
    for (int r = 0; r < 4; ++r)
#pragma unroll
        for (int dd = 1; dd < 16; dd <<= 1) lm[r] = fmaxf(lm[r], __shfl_xor(lm[r], dd));
    if (ln == 0) {
#pragma unroll
        for (int r = 0; r < 4; ++r) pmax[sh * 32 + rowb + r] = lm[r];
    }
    __syncthreads();
    float Mr[4], sum[4];
#pragma unroll
    for (int r = 0; r < 4; ++r) {
        Mr[r] = fmaxf(pmax[rowb + r], pmax[32 + rowb + r]) * scale;
        sum[r] = 0.f;
    }
#pragma unroll
    for (int i = 0; i < 9; ++i)
#pragma unroll
        for (int r = 0; r < 4; ++r) {
            float e = __expf(E[i][r] * scale - Mr[r]);   // -inf -> 0 exactly
            E[i][r] = e;
            sum[r] += e;
        }
#pragma unroll
    for (int r = 0; r < 4; ++r)
#pragma unroll
        for (int dd = 1; dd < 16; dd <<= 1) sum[r] += __shfl_xor(sum[r], dd);
    if (ln == 0) {
#pragma unroll
        for (int r = 0; r < 4; ++r) psum[sh * 32 + rowb + r] = sum[r];
    }
    __syncthreads();
    float inv[4];
#pragma unroll
    for (int r = 0; r < 4; ++r) inv[r] = 1.0f / (psum[rowb + r] + psum[32 + rowb + r]);
#pragma unroll
    for (int i = 0; i < 9; ++i) {
        const int col = sh * 144 + i * 16 + ln;
#pragma unroll
        for (int r = 0; r < 4; ++r)
            P[(rowb + r) * PROW + col] = (short)f2bf(E[i][r] * inv[r]);
    }
    __syncthreads();

    // ---- phase 3: O = P @ V; per q two staged steps (kg 0-4, 5-8), dbuf, 1 barrier/step ----
    short* Vbuf = (short*)(RAW + 19456);
    s16x8 pa[9];
#pragma unroll
    for (int kg = 0; kg < 9; ++kg)
        pa[kg] = *(const s16x8*)(P + (th * 16 + ln) * PROW + kg * 32 + g * 8);

    int sgc[9];
#pragma unroll
    for (int kg = 0; kg < 9; ++kg) sgc[kg] = min(sg0 + kg, 63);

    float maskv[4], rmax[4];
#pragma unroll
    for (int r = 0; r < 4; ++r) {
        maskv[r] = Mask[(size_t)b * T_DIM + t0 + rowb + r];
        rmax[r]  = -INFINITY;
    }

    // wave w stages ct = 4q+w, kg in [kgbase, kgbase+KG): slot (w*KG + e)
#define STAGE3(S, NB)                                                               \
    {                                                                               \
        const int q_ = (S) >> 1;                                                    \
        short* dstb = Vbuf + (NB) * 10240;                                          \
        const int ct_ = q_ * 4 + w;                                                 \
        if (((S) & 1) == 0) {                                                       \
            _Pragma("unroll")                                                       \
            for (int e = 0; e < 5; ++e)                                             \
                gll16(Vtb + ((size_t)(ct_ * 64 + sgc[e]) * 64 + lane) * 8,          \
                      dstb + (w * 5 + e) * 512);                                    \
        } else {                                                                    \
            _Pragma("unroll")                                                       \
            for (int e = 0; e < 4; ++e)                                             \
                gll16(Vtb + ((size_t)(ct_ * 64 + sgc[5 + e]) * 64 + lane) * 8,      \
                      dstb + (w * 4 + e) * 512);                                    \
        }                                                                           \
    }

    STAGE3(0, 0);
    __syncthreads();

    f32x4 O0 = zed, O1 = zed;
#pragma unroll 2
    for (int s = 0; s < 32; ++s) {
        const int cur = s & 1;
        if (s < 31) STAGE3(s + 1, cur ^ 1);
        const short* vb = Vbuf + cur * 10240;
        if ((s & 1) == 0) {
            O0 = zed; O1 = zed;
#pragma unroll
            for (int e = 0; e < 5; ++e) {
                s16x8 bv0 = *(const s16x8*)(vb + ((sh * 2    ) * 5 + e) * 512 + lane * 8);
                s16x8 bv1 = *(const s16x8*)(vb + ((sh * 2 + 1) * 5 + e) * 512 + lane * 8);
                O0 = __builtin_amdgcn_mfma_f32_16x16x32_bf16(pa[e], bv0, O0, 0, 0, 0);
                O1 = __builtin_amdgcn_mfma_f32_16x16x32_bf16(pa[e], bv1, O1, 0, 0, 0);
            }
        } else {
#pragma unroll
            for (int e = 0; e < 4; ++e) {
                s16x8 bv0 = *(const s16x8*)(vb + ((sh * 2    ) * 4 + e) * 512 + lane * 8);
                s16x8 bv1 = *(const s16x8*)(vb + ((sh * 2 + 1) * 4 + e) * 512 + lane * 8);
                O0 = __builtin_amdgcn_mfma_f32_16x16x32_bf16(pa[5 + e], bv0, O0, 0, 0, 0);
                O1 = __builtin_amdgcn_mfma_f32_16x16x32_bf16(pa[5 + e], bv1, O1, 0, 0, 0);
            }
#pragma unroll
            for (int r = 0; r < 4; ++r) {
                rmax[r] = fmaxf(rmax[r], O0[r] * maskv[r]);
                rmax[r] = fmaxf(rmax[r], O1[r] * maskv[r]);
            }
        }
        __syncthreads();
    }

#pragma unroll
    for (int r = 0; r < 4; ++r)
#pragma unroll
        for (int dd = 1; dd < 16; dd <<= 1) rmax[r] = fmaxf(rmax[r], __shfl_xor(rmax[r], dd));
    if (ln == 0) {
#pragma unroll
        for (int r = 0; r < 4; ++r) red[sh * 32 + rowb + r] = rmax[r];
    }
    __syncthreads();
    if (tid < 32)
        wsrow[(size_t)b * T_DIM + t0 + tid] = fmaxf(red[tid], red[32 + tid]);
}

// ============ fallback (round-1, verified): K/V staged per block, Vt row-major ============
__global__ __launch_bounds__(256, 2)
void attn_band_mfma(const float* __restrict__ Q, const float* __restrict__ K,
                    const unsigned short* __restrict__ Vt,
                    const float* __restrict__ Mask, const int* __restrict__ m_ptr,
                    float* __restrict__ wsrow)
{
    __shared__ __align__(16) char smem_raw[57600];
    short* SM = (short*)smem_raw;
    short* Kc = SM;
    short* Qc = SM + 288 * KROW;
    short* P  = SM;
    short* Vl = SM + 32 * PROW;
    float* pmax = (float*)(smem_raw + 56832);
    float* psum = pmax + 64;
    float* red  = psum + 64;

    const int h = blockIdx.x;
    const int logical = (h & 7) * 64 + (h >> 3);
    const int b  = logical >> 6;
    const int t0 = (logical & 63) * TB;

    const int tid = threadIdx.x;
    const int w = tid >> 6, lane = tid & 63, g = lane >> 4, ln = lane & 15;
    const int th = w >> 1, sh = w & 1;
    const int m  = m_ptr[0];

    const int s_lo = max(0, t0 - m);
    const int s_hi = min(T_DIM - 1, t0 + TB - 1 + m);

    const float* Qb = Q + (size_t)b * T_DIM * C_DIM;
    const float* Kb = K + (size_t)b * T_DIM * C_DIM;
    const unsigned short* Vtb = Vt + (size_t)b * C_DIM * T_DIM;

    f32x4 E[9];
    f32x4 zed = {0.f, 0.f, 0.f, 0.f};
#pragma unroll
    for (int i = 0; i < 9; ++i) E[i] = zed;

    for (int cc = 0; cc < C_DIM / 64; ++cc) {
        const int c0 = cc * 64;
        __syncthreads();
        for (int u = tid; u < 288 * 8; u += 256) {
            const int su = u >> 3, un = u & 7;
            const int s = min(s_lo + su, T_DIM - 1);
            const float4* src = (const float4*)(Kb + (size_t)s * C_DIM + c0 + un * 8);
            float4 x = src[0], y = src[1];
            uint4 o; o.x = pk2(x.x, x.y); o.y = pk2(x.z, x.w);
            o.z = pk2(y.x, y.y); o.w = pk2(y.z, y.w);
            *(uint4*)(Kc + su * KROW + un * 8) = o;
        }
        {
            const int su = tid >> 3, un = tid & 7;
            const float4* src = (const float4*)(Qb + (size_t)(t0 + su) * C_DIM + c0 + un * 8);
            float4 x = src[0], y = src[1];
            uint4 o; o.x = pk2(x.x, x.y); o.y = pk2(x.z, x.w);
            o.z = pk2(y.x, y.y); o.w = pk2(y.z, y.w);
            *(uint4*)(Qc + su * KROW + un * 8) = o;
        }
        __syncthreads();
        s16x8 aq[2];
#pragma unroll
        for (int kk = 0; kk < 2; ++kk)
            aq[kk] = *(const s16x8*)(Qc + (th * 16 + ln) * KROW + kk * 32 + g * 8);
#pragma unroll
        for (int i = 0; i < 9; ++i) {
            const int srow2 = (sh * 9 + i) * 16 + ln;
#pragma unroll
            for (int kk = 0; kk < 2; ++kk) {
                s16x8 bk = *(const s16x8*)(Kc + srow2 * KROW + kk * 32 + g * 8);
                E[i] = __builtin_amdgcn_mfma_f32_16x16x32_bf16(aq[kk], bk, E[i], 0, 0, 0);
            }
        }
    }

    const float scale = 0.03125f;
    const int rowb = th * 16 + g * 4;
    float lm[4];
#pragma unroll
    for (int r = 0; r < 4; ++r) lm[r] = -INFINITY;
    const int s_base = s_lo + sh * 144 + ln;
#pragma unroll
    for (int i = 0; i < 9; ++i) {
        const int s = s_base + i * 16;
#pragma unroll
        for (int r = 0; r < 4; ++r) {
            const int t = t0 + rowb + r;
            int d = t - s; d = d < 0 ? -d : d;
            const bool valid = (s <= s_hi) && (d <= m);
            float e = valid ? E[i][r] : -INFINITY;
            E[i][r] = e;
            lm[r] = fmaxf(lm[r], e);
        }
    }
#pragma unroll
    for (int r = 0; r < 4; ++r)
#pragma unroll
        for (int dd = 1; dd < 16; dd <<= 1) lm[r] = fmaxf(lm[r], __shfl_xor(lm[r], dd));
    if (ln == 0) {
#pragma unroll
        for (int r = 0; r < 4; ++r) pmax[sh * 32 + rowb + r] = lm[r];
    }
    __syncthreads();
    float Mr[4], sum[4];
#pragma unroll
    for (int r = 0; r < 4; ++r) {
        Mr[r] = fmaxf(pmax[rowb + r], pmax[32 + rowb + r]) * scale;
        sum[r] = 0.f;
    }
#pragma unroll
    for (int i = 0; i < 9; ++i)
#pragma unroll
        for (int r = 0; r < 4; ++r) {
            float e = __expf(E[i][r] * scale - Mr[r]);
            E[i][r] = e;
            sum[r] += e;
        }
#pragma unroll
    for (int r = 0; r < 4; ++r)
#pragma unroll
        for (int dd = 1; dd < 16; dd <<= 1) sum[r] += __shfl_xor(sum[r], dd);
    if (ln == 0) {
#pragma unroll
        for (int r = 0; r < 4; ++r) psum[sh * 32 + rowb + r] = sum[r];
    }
    __syncthreads();
    float inv[4];
#pragma unroll
    for (int r = 0; r < 4; ++r) inv[r] = 1.0f / (psum[rowb + r] + psum[32 + rowb + r]);
#pragma unroll
    for (int i = 0; i < 9; ++i) {
        const int col = sh * 144 + i * 16 + ln;
#pragma unroll
        for (int r = 0; r < 4; ++r)
            P[(rowb + r) * PROW + col] = (short)f2bf(E[i][r] * inv[r]);
    }
    __syncthreads();

    s16x8 pa[9];
#pragma unroll
    for (int kg = 0; kg < 9; ++kg)
        pa[kg] = *(const s16x8*)(P + (th * 16 + ln) * PROW + kg * 32 + g * 8);

    float maskv[4], rmax[4];
#pragma unroll
    for (int r = 0; r < 4; ++r) {
        maskv[r] = Mask[(size_t)b * T_DIM + t0 + rowb + r];
        rmax[r]  = -INFINITY;
    }

    for (int cc = 0; cc < C_DIM / 64; ++cc) {
        __syncthreads();
        for (int i2 = tid; i2 < 64 * 36; i2 += 256) {
            const int cr = i2 / 36, un = i2 - cr * 36;
            const int sb = min(s_lo + un * 8, T_DIM - 8);
            uint4 x = *(const uint4*)(Vtb + (size_t)(cc * 64 + cr) * T_DIM + sb);
            *(uint4*)(Vl + cr * PROW + un * 8) = x;
        }
        __syncthreads();
#pragma unroll
        for (int nbi = 0; nbi < 2; ++nbi) {
            const int crow = sh * 32 + nbi * 16 + ln;
            f32x4 O = zed;
#pragma unroll
            for (int kg = 0; kg < 9; ++kg) {
                s16x8 bv = *(const s16x8*)(Vl + crow * PROW + kg * 32 + g * 8);
                O = __builtin_amdgcn_mfma_f32_16x16x32_bf16(pa[kg], bv, O, 0, 0, 0);
            }
#pragma unroll
            for (int r = 0; r < 4; ++r)
                rmax[r] = fmaxf(rmax[r], O[r] * maskv[r]);
        }
    }
#pragma unroll
    for (int r = 0; r < 4; ++r)
#pragma unroll
        for (int dd = 1; dd < 16; dd <<= 1) rmax[r] = fmaxf(rmax[r], __shfl_xor(rmax[r], dd));
    if (ln == 0) {
#pragma unroll
        for (int r = 0; r < 4; ++r) red[sh * 32 + rowb + r] = rmax[r];
    }
    __syncthreads();
    if (tid < 32)
        wsrow[(size_t)b * T_DIM + t0 + tid] = fmaxf(red[tid], red[32 + tid]);
}

// out[b] = sum_t ws[b][t]
__global__ void reduce_b(const float* __restrict__ ws, float* __restrict__ out)
{
    const int b = blockIdx.x;
    float s = 0.f;
    for (int t = threadIdx.x; t < T_DIM; t += 256) s += ws[(size_t)b * T_DIM + t];
#pragma unroll
    for (int dd = 32; dd > 0; dd >>= 1) s += __shfl_xor(s, dd);
    __shared__ float acc[4];
    if ((threadIdx.x & 63) == 0) acc[threadIdx.x >> 6] = s;
    __syncthreads();
    if (threadIdx.x == 0) out[b] = acc[0] + acc[1] + acc[2] + acc[3];
}

extern "C" void kernel_launch(void* const* d_in, const int* in_sizes, int n_in,
                              void* d_out, int out_size, void* d_ws, size_t ws_size,
                              hipStream_t stream)
{
    const float* Q    = (const float*)d_in[0];
    const float* K    = (const float*)d_in[1];
    const float* V    = (const float*)d_in[2];
    const float* Mask = (const float*)d_in[3];
    const int*   m    = (const int*)d_in[4];
    float* out = (float*)d_out;

    const size_t frag_bytes = (size_t)B_DIM * T_DIM * C_DIM * 2;   // 33,554,432 per tensor
    const size_t need_main  = 2 * frag_bytes + (size_t)B_DIM * T_DIM * 4;

    if (ws_size >= need_main) {
        unsigned short* Kt  = (unsigned short*)d_ws;
        unsigned short* Vtt = (unsigned short*)((char*)d_ws + frag_bytes);
        float* wsrow = (float*)((char*)d_ws + 2 * frag_bytes);
        tile_k<<<dim3(128, B_DIM), 256, 0, stream>>>(K, Kt);
        transpose_vx<<<dim3(T_DIM / 64, C_DIM / 64, B_DIM), 256, 0, stream>>>(V, Vtt, 1);
        attn_band_tiled<<<dim3((T_DIM / TB) * B_DIM), 256, 0, stream>>>(Q, Kt, Vtt, Mask, m, wsrow);
        reduce_b<<<B_DIM, 256, 0, stream>>>(wsrow, out);
    } else {
        unsigned short* Vt = (unsigned short*)d_ws;
        float* wsrow = (float*)((char*)d_ws + frag_bytes);
        transpose_vx<<<dim3(T_DIM / 64, C_DIM / 64, B_DIM), 256, 0, stream>>>(V, Vt, 0);
        attn_band_mfma<<<dim3((T_DIM / TB) * B_DIM), 256, 0, stream>>>(Q, K, Vt, Mask, m, wsrow);
        reduce_b<<<B_DIM, 256, 0, stream>>>(wsrow, out);
    }
}